// Round 15
// baseline (586.834 us; speedup 1.0000x reference)
//
#include <hip/hip_runtime.h>
#include <hip/hip_bf16.h>

#define NN 50000
#define NE 800000
#define D 128
#define NL 5
#define NR 2048
#define NO 65
#define FILL_NB 1024

typedef unsigned short ushort_t;
typedef __attribute__((ext_vector_type(8))) short bf16x8;
typedef __attribute__((ext_vector_type(4))) float f32x4;

// h16/z16 stored SLICE-MAJOR: [4][NN][32] bf16 — dim d of node n lives at
// ((d>>5)*NN + n)*32 + (d&31). One 32-dim slice per XCD-pinned gather block.

__device__ inline float bflo(unsigned u) {
    return __builtin_bit_cast(float, u << 16);
}
__device__ inline float bfhi(unsigned u) {
    return __builtin_bit_cast(float, u & 0xFFFF0000u);
}
__device__ inline ushort_t f2bf(float f) {
    unsigned u = __builtin_bit_cast(unsigned, f);
    u = (u + 0x7FFF + ((u >> 16) & 1)) >> 16;   // RNE
    return (ushort_t)u;
}
__device__ inline unsigned pk2(float a, float b) {
    return (unsigned)f2bf(a) | ((unsigned)f2bf(b) << 16);
}
__device__ inline void acc8(float* a, uint4 v) {
    a[0] += bflo(v.x); a[1] += bfhi(v.x);
    a[2] += bflo(v.y); a[3] += bfhi(v.y);
    a[4] += bflo(v.z); a[5] += bfhi(v.z);
    a[6] += bflo(v.w); a[7] += bfhi(v.w);
}

// --- combined init: h0 (sliced bf16) + W1t/W2t transpose + degree histogram ---
__global__ void k_initw(const int* __restrict__ x, const float* __restrict__ ke,
                        const float* __restrict__ ve, ushort_t* __restrict__ h16,
                        const float* __restrict__ W1, ushort_t* __restrict__ W1t,
                        const float* __restrict__ W2, ushort_t* __restrict__ W2t,
                        const int* __restrict__ ei, int* __restrict__ deg) {
    int i = blockIdx.x * blockDim.x + threadIdx.x;
    if (i < NN * 32) {
        int node = i >> 5, f4 = (i & 31) * 4;
        float4 a = *(const float4*)&ke[(size_t)x[node * 2 + 0] * D + f4];
        float4 b = *(const float4*)&ve[(size_t)x[node * 2 + 1] * D + f4];
        uint2 o;
        o.x = pk2(a.x + b.x, a.y + b.y);
        o.y = pk2(a.z + b.z, a.w + b.w);
        const int s = f4 >> 5, off = f4 & 31;
        *(uint2*)&h16[((size_t)s * NN + node) * 32 + off] = o;
        return;
    }
    int j = i - NN * 32;
    if (j < NL * 32768) {               // W1t[l][n(256)][k(128)]
        int l = j / 32768, r = j % 32768;
        int n = r >> 7, k = r & 127;
        W1t[j] = f2bf(W1[l * 32768 + k * 256 + n]);
        return;
    }
    j -= NL * 32768;
    if (j < NL * 32768) {               // W2t[l][n(128)][k(256)]
        int l = j / 32768, r = j % 32768;
        int n = r >> 8, k = r & 255;
        W2t[j] = f2bf(W2[l * 32768 + k * 128 + n]);
        return;
    }
    j -= NL * 32768;
    if (j < NE) atomicAdd(&deg[ei[NE + j]], 1);
}

__global__ void k_scan1(const int* __restrict__ deg, int* __restrict__ incl,
                        int* __restrict__ bsums) {
    __shared__ int s[256];
    int t = threadIdx.x, i = blockIdx.x * 256 + t;
    int v = (i < NN) ? deg[i] : 0;
    s[t] = v; __syncthreads();
    for (int off = 1; off < 256; off <<= 1) {
        int u = (t >= off) ? s[t - off] : 0;
        __syncthreads();
        s[t] += u; __syncthreads();
    }
    if (i < NN) incl[i] = s[t];
    if (t == 255) bsums[blockIdx.x] = s[255];
}

__global__ void k_scan2(int* __restrict__ bsums, int nb) {
    __shared__ int s[256];
    int t = threadIdx.x;
    int v = (t < nb) ? bsums[t] : 0;
    s[t] = v; __syncthreads();
    for (int off = 1; off < 256; off <<= 1) {
        int u = (t >= off) ? s[t - off] : 0;
        __syncthreads();
        s[t] += u; __syncthreads();
    }
    if (t < nb) bsums[t] = s[t] - v;   // exclusive
}

__global__ void k_scan3(const int* __restrict__ deg, const int* __restrict__ incl,
                        const int* __restrict__ bsums, int* __restrict__ rs,
                        int* __restrict__ cur) {
    int i = blockIdx.x * blockDim.x + threadIdx.x;
    if (i >= NN) return;
    int ex = incl[i] - deg[i] + bsums[i >> 8];
    rs[i] = ex; cur[i] = ex;
    if (i == 0) rs[NN] = NE;
}

// XCD-partitioned fill: block b serves dst-partition b&7 (6250 nodes);
// csrc/cur lines for a partition are dirtied in exactly one XCD's L2.
__global__ void k_fill(const int* __restrict__ ei, int* __restrict__ cur,
                       ushort_t* __restrict__ csrc) {
    const int part = blockIdx.x & 7;
    const int j = blockIdx.x >> 3;
    const int lo = part * (NN / 8), hi = lo + (NN / 8);
    for (int e = j * 256 + threadIdx.x; e < NE; e += (FILL_NB / 8) * 256) {
        const int d = ei[NE + e];
        if (d >= lo && d < hi) {
            const int pos = atomicAdd(&cur[d], 1);
            csrc[pos] = (ushort_t)ei[e];    // src < 50000 < 65536
        }
    }
}

// ------- aggregate (sliced): z16[s] = bf16((1+eps)*h[s] + sum_in h[s][src]) -----
// block = 256 thr = 4 waves, 32 nodes x ONE 32-dim slice (blockIdx&3; XCD-pinned).
// wave: 8 nodes (grp), 2 edge-phases (q) x batch-8 (stride 2) = 16 edges/node
// per iter, 8 row-loads in flight per lane; 4 lanes per 64B slice row (p).
__global__ void __launch_bounds__(256) k_agg(const ushort_t* __restrict__ h16,
                                             const int* __restrict__ rs,
                                             const ushort_t* __restrict__ csrc,
                                             const float* __restrict__ epsArr, int layer,
                                             ushort_t* __restrict__ z16) {
    const int s = blockIdx.x & 3;
    const int nb = blockIdx.x >> 2;
    const int wv = threadIdx.x >> 6;
    const int lane = threadIdx.x & 63;
    const int grp = lane >> 3;            // which of the wave's 8 nodes
    const int q = (lane >> 2) & 1;        // edge phase (2)
    const int p = lane & 3;               // which uint4 of the 64B slice row
    const int node = nb * 32 + wv * 8 + grp;
    if (node >= NN) return;               // uniform per q-pair (bit2 not in grp)
    const uint4* H4 = (const uint4*)(h16 + (size_t)s * NN * 32);
    const int myE0 = rs[node], myE1 = rs[node + 1];
    const uint4 own = H4[(size_t)node * 4 + p];
    const uint4 z4 = {0u, 0u, 0u, 0u};
    float acc[8] = {0.f, 0.f, 0.f, 0.f, 0.f, 0.f, 0.f, 0.f};
    for (int base = myE0 + q; base < myE1; base += 16) {
        int ee[8];
        #pragma unroll
        for (int k = 0; k < 8; ++k) {
            const int e = base + 2 * k;
            ee[k] = (e < myE1) ? (int)csrc[e] : -1;
        }
        uint4 vv[8];
        #pragma unroll
        for (int k = 0; k < 8; ++k)
            vv[k] = (ee[k] >= 0) ? H4[(size_t)ee[k] * 4 + p] : z4;
        #pragma unroll
        for (int k = 0; k < 8; ++k) acc8(acc, vv[k]);
    }
    #pragma unroll
    for (int k = 0; k < 8; ++k)           // reduce over q (bit 2); grp,p kept
        acc[k] += __shfl_xor(acc[k], 4);
    if (q == 0) {
        const float epsl = 1.f + epsArr[layer];
        float r0 = acc[0] + epsl * bflo(own.x), r1 = acc[1] + epsl * bfhi(own.x);
        float r2 = acc[2] + epsl * bflo(own.y), r3 = acc[3] + epsl * bfhi(own.y);
        float r4 = acc[4] + epsl * bflo(own.z), r5 = acc[5] + epsl * bfhi(own.z);
        float r6 = acc[6] + epsl * bflo(own.w), r7 = acc[7] + epsl * bfhi(own.w);
        uint4 o;
        o.x = pk2(r0, r1); o.y = pk2(r2, r3);
        o.z = pk2(r4, r5); o.w = pk2(r6, r7);
        ((uint4*)(z16 + (size_t)s * NN * 32))[(size_t)node * 4 + p] = o;
    }
}

// ============ persistent MFMA MLP + residual + LayerNorm (sliced I/O) ============
__global__ void __launch_bounds__(512, 2) k_mlp(
        const ushort_t* __restrict__ z16,
        const ushort_t* __restrict__ h16i, ushort_t* __restrict__ h16o,
        const int layer,
        const ushort_t* __restrict__ W1t, const float* __restrict__ b1,
        const ushort_t* __restrict__ W2t, const float* __restrict__ b2,
        const float* __restrict__ lng, const float* __restrict__ lnb) {
    __shared__ ushort_t ts[32 * 256];        // 16 KB, XOR-swizzled (512 B rows)
    __shared__ float red[2][16][4][2];       // cross-wave LN partials
    const int t = threadIdx.x;
    const int lane = t & 63, w = t >> 6;     // 8 waves
    const int lr = lane & 15, lk = lane >> 4;
    const int rt_w = w & 1, ch = w >> 1;     // ch = col-slice (0..3)

    // ---- register-cache weight fragments (once per block) ----
    const ushort_t* W1p = W1t + (size_t)layer * 256 * 128;
    const ushort_t* W2p = W2t + (size_t)layer * 128 * 256;
    bf16x8 fa1[2][4];
    #pragma unroll
    for (int nt = 0; nt < 2; ++nt)
        #pragma unroll
        for (int kk = 0; kk < 4; ++kk)
            fa1[nt][kk] = *(const bf16x8*)(W1p + (size_t)((w * 2 + nt) * 16 + lr) * 128 + kk * 32 + lk * 8);
    bf16x8 fa2[2][8];
    #pragma unroll
    for (int nt = 0; nt < 2; ++nt)
        #pragma unroll
        for (int kk = 0; kk < 8; ++kk)
            fa2[nt][kk] = *(const bf16x8*)(W2p + (size_t)((ch * 2 + nt) * 16 + lr) * 256 + kk * 32 + lk * 8);

    // per-lane bias/LN params (fixed columns)
    float4 bb1[2], bb2[2], g4[2], be4[2];
    #pragma unroll
    for (int nt = 0; nt < 2; ++nt) {
        bb1[nt] = *(const float4*)&b1[layer * 256 + (w * 2 + nt) * 16 + lk * 4];
        const int c = (ch * 2 + nt) * 16 + lk * 4;
        bb2[nt] = *(const float4*)&b2[layer * 128 + c];
        g4[nt]  = *(const float4*)&lng[layer * 128 + c];
        be4[nt] = *(const float4*)&lnb[layer * 128 + c];
    }

    const int NT = (NN + 31) / 32;
    const int myrow = rt_w * 16 + lr;
    for (int tile = blockIdx.x; tile < NT; tile += gridDim.x) {
        const int row0 = tile * 32;
        const int node = row0 + myrow;

        // residual prefetch
        uint2 hres[2] = {{0u, 0u}, {0u, 0u}};
        if (node < NN) {
            #pragma unroll
            for (int nt = 0; nt < 2; ++nt)
                hres[nt] = *(const uint2*)&h16i[((size_t)ch * NN + node) * 32 + nt * 16 + lk * 4];
        }

        // ---- phase 1: C1^T = W1(A) x z(B); z slice = kk exactly ----
        f32x4 acc1[2][2];
        #pragma unroll
        for (int nt = 0; nt < 2; ++nt)
            #pragma unroll
            for (int rt = 0; rt < 2; ++rt) acc1[nt][rt] = (f32x4){0.f, 0.f, 0.f, 0.f};
        #pragma unroll
        for (int kk = 0; kk < 4; ++kk) {
            bf16x8 bv[2];
            #pragma unroll
            for (int rt = 0; rt < 2; ++rt) {
                const int zrow = row0 + rt * 16 + lr;
                bv[rt] = (zrow < NN)
                    ? *(const bf16x8*)(z16 + ((size_t)kk * NN + zrow) * 32 + lk * 8)
                    : (bf16x8){0, 0, 0, 0, 0, 0, 0, 0};
            }
            #pragma unroll
            for (int nt = 0; nt < 2; ++nt)
                #pragma unroll
                for (int rt = 0; rt < 2; ++rt)
                    acc1[nt][rt] = __builtin_amdgcn_mfma_f32_16x16x32_bf16(fa1[nt][kk], bv[rt], acc1[nt][rt], 0, 0, 0);
        }
        // bias + relu -> ts (lane holds 4 consecutive n-cols at one z-row)
        #pragma unroll
        for (int nt = 0; nt < 2; ++nt) {
            const int nc = (w * 2 + nt) * 16 + lk * 4;
            #pragma unroll
            for (int rt = 0; rt < 2; ++rt) {
                const int zrow = rt * 16 + lr;
                unsigned lo = pk2(fmaxf(acc1[nt][rt][0] + bb1[nt].x, 0.f),
                                  fmaxf(acc1[nt][rt][1] + bb1[nt].y, 0.f));
                unsigned hi = pk2(fmaxf(acc1[nt][rt][2] + bb1[nt].z, 0.f),
                                  fmaxf(acc1[nt][rt][3] + bb1[nt].w, 0.f));
                const int byte = (zrow * 512 + nc * 2) ^ ((zrow & 7) << 4);
                uint2 o; o.x = lo; o.y = hi;
                *(uint2*)((char*)ts + byte) = o;
            }
        }
        __syncthreads();

        // ---- phase 2: C2^T = W2(A) x t(B); rows rt_w*16.., cols ch*32.. ----
        f32x4 acc2[2];
        acc2[0] = (f32x4){0.f, 0.f, 0.f, 0.f};
        acc2[1] = (f32x4){0.f, 0.f, 0.f, 0.f};
        #pragma unroll
        for (int kk = 0; kk < 8; ++kk) {
            const int byte = (myrow * 512 + kk * 64 + lk * 16) ^ ((myrow & 7) << 4);
            const bf16x8 bv = *(const bf16x8*)((const char*)ts + byte);
            acc2[0] = __builtin_amdgcn_mfma_f32_16x16x32_bf16(fa2[0][kk], bv, acc2[0], 0, 0, 0);
            acc2[1] = __builtin_amdgcn_mfma_f32_16x16x32_bf16(fa2[1][kk], bv, acc2[1], 0, 0, 0);
        }

        // ---- bias + residual + LN partials (lane: 8 cols of row `myrow`) ----
        float vals[2][4];
        float s = 0.f, ss = 0.f;
        #pragma unroll
        for (int nt = 0; nt < 2; ++nt) {
            float v0 = acc2[nt][0] + bb2[nt].x + bflo(hres[nt].x);
            float v1 = acc2[nt][1] + bb2[nt].y + bfhi(hres[nt].x);
            float v2 = acc2[nt][2] + bb2[nt].z + bflo(hres[nt].y);
            float v3 = acc2[nt][3] + bb2[nt].w + bfhi(hres[nt].y);
            vals[nt][0] = v0; vals[nt][1] = v1; vals[nt][2] = v2; vals[nt][3] = v3;
            s += v0 + v1 + v2 + v3;
            ss += v0 * v0 + v1 * v1 + v2 * v2 + v3 * v3;
        }
        s  += __shfl_xor(s, 16);  s  += __shfl_xor(s, 32);
        ss += __shfl_xor(ss, 16); ss += __shfl_xor(ss, 32);
        if (lk == 0) {
            red[rt_w][lr][ch][0] = s;
            red[rt_w][lr][ch][1] = ss;
        }
        __syncthreads();

        // cross-wave combine (4 col-slices per row)
        float st = red[rt_w][lr][0][0] + red[rt_w][lr][1][0] + red[rt_w][lr][2][0] + red[rt_w][lr][3][0];
        float sst = red[rt_w][lr][0][1] + red[rt_w][lr][1][1] + red[rt_w][lr][2][1] + red[rt_w][lr][3][1];
        const float mu = st * (1.f / 128.f);
        const float rstd = rsqrtf(sst * (1.f / 128.f) - mu * mu + 1e-5f);
        if (node < NN) {
            #pragma unroll
            for (int nt = 0; nt < 2; ++nt) {
                float o0 = (vals[nt][0] - mu) * rstd * g4[nt].x + be4[nt].x;
                float o1 = (vals[nt][1] - mu) * rstd * g4[nt].y + be4[nt].y;
                float o2 = (vals[nt][2] - mu) * rstd * g4[nt].z + be4[nt].z;
                float o3 = (vals[nt][3] - mu) * rstd * g4[nt].w + be4[nt].w;
                uint2 pkd; pkd.x = pk2(o0, o1); pkd.y = pk2(o2, o3);
                *(uint2*)&h16o[((size_t)ch * NN + node) * 32 + nt * 16 + lk * 4] = pkd;
            }
        }
    }
}

// ---------------- readout: out = h[roots] @ W_out (sliced h) ----------------
__global__ void __launch_bounds__(256) k_out(const ushort_t* __restrict__ h,
                                             const int* __restrict__ roots,
                                             const float* __restrict__ Wo,
                                             float* __restrict__ out) {
    __shared__ float hs[16 * 128];
    int t = threadIdx.x;
    int r0 = blockIdx.x * 16;
    for (int i = t; i < 16 * 32; i += 256) {
        int row = i >> 5, u = i & 31;
        const int sl = u >> 3, off = (u & 7) * 4;
        uint2 v = *(const uint2*)&h[((size_t)sl * NN + roots[r0 + row]) * 32 + off];
        hs[row * 128 + u * 4 + 0] = bflo(v.x);
        hs[row * 128 + u * 4 + 1] = bfhi(v.x);
        hs[row * 128 + u * 4 + 2] = bflo(v.y);
        hs[row * 128 + u * 4 + 3] = bfhi(v.y);
    }
    __syncthreads();
    for (int o = t; o < 16 * NO; o += 256) {
        int j = o / NO, c = o % NO;
        float s = 0.f;
        for (int k = 0; k < 128; ++k) s += hs[j * 128 + k] * Wo[k * NO + c];
        out[(r0 + j) * NO + c] = s;
    }
}

extern "C" void kernel_launch(void* const* d_in, const int* in_sizes, int n_in,
                              void* d_out, int out_size, void* d_ws, size_t ws_size,
                              hipStream_t stream) {
    const int*   x    = (const int*)d_in[0];
    const int*   ei   = (const int*)d_in[1];
    const int*   roots= (const int*)d_in[2];
    const float* ke   = (const float*)d_in[3];
    const float* ve   = (const float*)d_in[4];
    const float* eps  = (const float*)d_in[5];
    const float* W1   = (const float*)d_in[6];
    const float* b1   = (const float*)d_in[7];
    const float* W2   = (const float*)d_in[8];
    const float* b2   = (const float*)d_in[9];
    const float* g    = (const float*)d_in[10];
    const float* bt   = (const float*)d_in[11];
    const float* Wo   = (const float*)d_in[12];
    float* out = (float*)d_out;

    char* ws = (char*)d_ws;
    size_t off = 0;
    auto alloc = [&](size_t bytes) {
        void* p = ws + off;
        off += (bytes + 255) & ~(size_t)255;
        return p;
    };
    ushort_t* h16A = (ushort_t*)alloc((size_t)NN * D * 2);
    ushort_t* h16B = (ushort_t*)alloc((size_t)NN * D * 2);
    ushort_t* z16  = (ushort_t*)alloc((size_t)NN * D * 2);
    ushort_t* W1tb = (ushort_t*)alloc((size_t)NL * 256 * 128 * 2);
    ushort_t* W2tb = (ushort_t*)alloc((size_t)NL * 128 * 256 * 2);
    int* deg  = (int*)alloc((size_t)NN * 4);
    int* incl = (int*)alloc((size_t)NN * 4);
    int* bsum = (int*)alloc(256 * 4);
    int* rs   = (int*)alloc((size_t)(NN + 1) * 4);
    int* cur  = (int*)alloc((size_t)NN * 4);
    ushort_t* csrc = (ushort_t*)alloc((size_t)NE * 2);

    hipMemsetAsync(deg, 0, (size_t)NN * 4, stream);

    const int initTot = NN * 32 + 2 * NL * 32768 + NE;
    k_initw<<<(initTot + 255) / 256, 256, 0, stream>>>(x, ke, ve, h16A, W1, W1tb, W2, W2tb, ei, deg);
    int nb = (NN + 255) / 256;
    k_scan1<<<nb, 256, 0, stream>>>(deg, incl, bsum);
    k_scan2<<<1, 256, 0, stream>>>(bsum, nb);
    k_scan3<<<nb, 256, 0, stream>>>(deg, incl, bsum, rs, cur);
    k_fill<<<FILL_NB, 256, 0, stream>>>(ei, cur, csrc);

    const int aggBlocks = ((NN + 31) / 32) * 4;   // 1563 node-blocks x 4 slices
    for (int l = 0; l < NL; ++l) {
        const ushort_t* hi = (l & 1) ? h16B : h16A;
        ushort_t*       ho = (l & 1) ? h16A : h16B;
        k_agg<<<aggBlocks, 256, 0, stream>>>(hi, rs, csrc, eps, l, z16);
        k_mlp<<<512, 512, 0, stream>>>(z16, hi, ho, l, W1tb, b1, W2tb, b2, g, bt);
    }
    k_out<<<NR / 16, 256, 0, stream>>>(h16B, roots, Wo, out);
}

// Round 16
// 417.876 us; speedup vs baseline: 1.4043x; 1.4043x over previous
//
#include <hip/hip_runtime.h>
#include <hip/hip_bf16.h>

#define NN 50000
#define NE 800000
#define D 128
#define NL 5
#define NR 2048
#define NO 65
#define FILL_NB 1024

typedef unsigned short ushort_t;
typedef __attribute__((ext_vector_type(8))) short bf16x8;
typedef __attribute__((ext_vector_type(4))) float f32x4;

// h16/z16 stored SLICE-MAJOR: [4][NN][32] bf16 — dim d of node n lives at
// ((d>>5)*NN + n)*32 + (d&31). One 32-dim slice per XCD-pinned gather block.

__device__ inline float bflo(unsigned u) {
    return __builtin_bit_cast(float, u << 16);
}
__device__ inline float bfhi(unsigned u) {
    return __builtin_bit_cast(float, u & 0xFFFF0000u);
}
__device__ inline ushort_t f2bf(float f) {
    unsigned u = __builtin_bit_cast(unsigned, f);
    u = (u + 0x7FFF + ((u >> 16) & 1)) >> 16;   // RNE
    return (ushort_t)u;
}
__device__ inline unsigned pk2(float a, float b) {
    return (unsigned)f2bf(a) | ((unsigned)f2bf(b) << 16);
}
__device__ inline void acc8(float* a, uint4 v) {
    a[0] += bflo(v.x); a[1] += bfhi(v.x);
    a[2] += bflo(v.y); a[3] += bfhi(v.y);
    a[4] += bflo(v.z); a[5] += bfhi(v.z);
    a[6] += bflo(v.w); a[7] += bfhi(v.w);
}

// --- combined init: h0 (sliced bf16) + W1t/W2t transpose + degree histogram ---
__global__ void k_initw(const int* __restrict__ x, const float* __restrict__ ke,
                        const float* __restrict__ ve, ushort_t* __restrict__ h16,
                        const float* __restrict__ W1, ushort_t* __restrict__ W1t,
                        const float* __restrict__ W2, ushort_t* __restrict__ W2t,
                        const int* __restrict__ ei, int* __restrict__ deg) {
    int i = blockIdx.x * blockDim.x + threadIdx.x;
    if (i < NN * 32) {
        int node = i >> 5, f4 = (i & 31) * 4;
        float4 a = *(const float4*)&ke[(size_t)x[node * 2 + 0] * D + f4];
        float4 b = *(const float4*)&ve[(size_t)x[node * 2 + 1] * D + f4];
        uint2 o;
        o.x = pk2(a.x + b.x, a.y + b.y);
        o.y = pk2(a.z + b.z, a.w + b.w);
        const int s = f4 >> 5, off = f4 & 31;
        *(uint2*)&h16[((size_t)s * NN + node) * 32 + off] = o;
        return;
    }
    int j = i - NN * 32;
    if (j < NL * 32768) {               // W1t[l][n(256)][k(128)]
        int l = j / 32768, r = j % 32768;
        int n = r >> 7, k = r & 127;
        W1t[j] = f2bf(W1[l * 32768 + k * 256 + n]);
        return;
    }
    j -= NL * 32768;
    if (j < NL * 32768) {               // W2t[l][n(128)][k(256)]
        int l = j / 32768, r = j % 32768;
        int n = r >> 8, k = r & 255;
        W2t[j] = f2bf(W2[l * 32768 + k * 128 + n]);
        return;
    }
    j -= NL * 32768;
    if (j < NE) atomicAdd(&deg[ei[NE + j]], 1);
}

__global__ void k_scan1(const int* __restrict__ deg, int* __restrict__ incl,
                        int* __restrict__ bsums) {
    __shared__ int s[256];
    int t = threadIdx.x, i = blockIdx.x * 256 + t;
    int v = (i < NN) ? deg[i] : 0;
    s[t] = v; __syncthreads();
    for (int off = 1; off < 256; off <<= 1) {
        int u = (t >= off) ? s[t - off] : 0;
        __syncthreads();
        s[t] += u; __syncthreads();
    }
    if (i < NN) incl[i] = s[t];
    if (t == 255) bsums[blockIdx.x] = s[255];
}

__global__ void k_scan2(int* __restrict__ bsums, int nb) {
    __shared__ int s[256];
    int t = threadIdx.x;
    int v = (t < nb) ? bsums[t] : 0;
    s[t] = v; __syncthreads();
    for (int off = 1; off < 256; off <<= 1) {
        int u = (t >= off) ? s[t - off] : 0;
        __syncthreads();
        s[t] += u; __syncthreads();
    }
    if (t < nb) bsums[t] = s[t] - v;   // exclusive
}

__global__ void k_scan3(const int* __restrict__ deg, const int* __restrict__ incl,
                        const int* __restrict__ bsums, int* __restrict__ rs,
                        int* __restrict__ cur) {
    int i = blockIdx.x * blockDim.x + threadIdx.x;
    if (i >= NN) return;
    int ex = incl[i] - deg[i] + bsums[i >> 8];
    rs[i] = ex; cur[i] = ex;
    if (i == 0) rs[NN] = NE;
}

// XCD-partitioned fill: block b serves dst-partition b&7 (6250 nodes);
// csrc/cur lines for a partition are dirtied in exactly one XCD's L2.
__global__ void k_fill(const int* __restrict__ ei, int* __restrict__ cur,
                       ushort_t* __restrict__ csrc) {
    const int part = blockIdx.x & 7;
    const int j = blockIdx.x >> 3;
    const int lo = part * (NN / 8), hi = lo + (NN / 8);
    for (int e = j * 256 + threadIdx.x; e < NE; e += (FILL_NB / 8) * 256) {
        const int d = ei[NE + e];
        if (d >= lo && d < hi) {
            const int pos = atomicAdd(&cur[d], 1);
            csrc[pos] = (ushort_t)ei[e];    // src < 50000 < 65536
        }
    }
}

// ------- aggregate (sliced): z16[s] = bf16((1+eps)*h[s] + sum_in h[s][src]) -----
// block = 256 thr = 4 waves, 16 nodes x ONE 32-dim slice (blockIdx&3; XCD-pinned).
// wave: 4 nodes (grp), 4 edge-phases (q) x batch-4 = 16 edges/node in flight,
// 4 lanes per 64B slice row (p). Proven R13 shape (batch-8 killed MLP via VGPR cap).
__global__ void __launch_bounds__(256) k_agg(const ushort_t* __restrict__ h16,
                                             const int* __restrict__ rs,
                                             const ushort_t* __restrict__ csrc,
                                             const float* __restrict__ epsArr, int layer,
                                             ushort_t* __restrict__ z16) {
    const int s = blockIdx.x & 3;
    const int nb = blockIdx.x >> 2;
    const int wv = threadIdx.x >> 6;
    const int lane = threadIdx.x & 63;
    const int grp = lane >> 4;            // which of the wave's 4 nodes
    const int q = (lane >> 2) & 3;        // edge phase (4)
    const int p = lane & 3;               // which uint4 of the 64B slice row
    const int node = nb * 16 + wv * 4 + grp;    // 3125*16 == NN exactly
    const uint4* H4 = (const uint4*)(h16 + (size_t)s * NN * 32);
    const int myE0 = rs[node], myE1 = rs[node + 1];
    const uint4 own = H4[(size_t)node * 4 + p];
    float acc[8] = {0.f, 0.f, 0.f, 0.f, 0.f, 0.f, 0.f, 0.f};
    for (int e = myE0 + q; e < myE1; e += 16) {
        const int ia = csrc[e];
        const int e1 = e + 4, e2 = e + 8, e3 = e + 12;
        const int ib = (e1 < myE1) ? (int)csrc[e1] : -1;
        const int ic = (e2 < myE1) ? (int)csrc[e2] : -1;
        const int id = (e3 < myE1) ? (int)csrc[e3] : -1;
        acc8(acc, H4[(size_t)ia * 4 + p]);
        if (ib >= 0) acc8(acc, H4[(size_t)ib * 4 + p]);
        if (ic >= 0) acc8(acc, H4[(size_t)ic * 4 + p]);
        if (id >= 0) acc8(acc, H4[(size_t)id * 4 + p]);
    }
    #pragma unroll
    for (int k = 0; k < 8; ++k) {         // reduce over q bits (4,8); grp,p kept
        acc[k] += __shfl_xor(acc[k], 4);
        acc[k] += __shfl_xor(acc[k], 8);
    }
    if (q == 0) {
        const float epsl = 1.f + epsArr[layer];
        float r0 = acc[0] + epsl * bflo(own.x), r1 = acc[1] + epsl * bfhi(own.x);
        float r2 = acc[2] + epsl * bflo(own.y), r3 = acc[3] + epsl * bfhi(own.y);
        float r4 = acc[4] + epsl * bflo(own.z), r5 = acc[5] + epsl * bfhi(own.z);
        float r6 = acc[6] + epsl * bflo(own.w), r7 = acc[7] + epsl * bfhi(own.w);
        uint4 o;
        o.x = pk2(r0, r1); o.y = pk2(r2, r3);
        o.z = pk2(r4, r5); o.w = pk2(r6, r7);
        ((uint4*)(z16 + (size_t)s * NN * 32))[(size_t)node * 4 + p] = o;
    }
}

// ============ persistent MFMA MLP + residual + LayerNorm (sliced I/O) ============
__global__ void __launch_bounds__(512, 2) k_mlp(
        const ushort_t* __restrict__ z16,
        const ushort_t* __restrict__ h16i, ushort_t* __restrict__ h16o,
        const int layer,
        const ushort_t* __restrict__ W1t, const float* __restrict__ b1,
        const ushort_t* __restrict__ W2t, const float* __restrict__ b2,
        const float* __restrict__ lng, const float* __restrict__ lnb) {
    __shared__ ushort_t ts[32 * 256];        // 16 KB, XOR-swizzled (512 B rows)
    __shared__ float red[2][16][4][2];       // cross-wave LN partials
    const int t = threadIdx.x;
    const int lane = t & 63, w = t >> 6;     // 8 waves
    const int lr = lane & 15, lk = lane >> 4;
    const int rt_w = w & 1, ch = w >> 1;     // ch = col-slice (0..3)

    // ---- register-cache weight fragments (once per block) ----
    const ushort_t* W1p = W1t + (size_t)layer * 256 * 128;
    const ushort_t* W2p = W2t + (size_t)layer * 128 * 256;
    bf16x8 fa1[2][4];
    #pragma unroll
    for (int nt = 0; nt < 2; ++nt)
        #pragma unroll
        for (int kk = 0; kk < 4; ++kk)
            fa1[nt][kk] = *(const bf16x8*)(W1p + (size_t)((w * 2 + nt) * 16 + lr) * 128 + kk * 32 + lk * 8);
    bf16x8 fa2[2][8];
    #pragma unroll
    for (int nt = 0; nt < 2; ++nt)
        #pragma unroll
        for (int kk = 0; kk < 8; ++kk)
            fa2[nt][kk] = *(const bf16x8*)(W2p + (size_t)((ch * 2 + nt) * 16 + lr) * 256 + kk * 32 + lk * 8);

    // per-lane bias/LN params (fixed columns)
    float4 bb1[2], bb2[2], g4[2], be4[2];
    #pragma unroll
    for (int nt = 0; nt < 2; ++nt) {
        bb1[nt] = *(const float4*)&b1[layer * 256 + (w * 2 + nt) * 16 + lk * 4];
        const int c = (ch * 2 + nt) * 16 + lk * 4;
        bb2[nt] = *(const float4*)&b2[layer * 128 + c];
        g4[nt]  = *(const float4*)&lng[layer * 128 + c];
        be4[nt] = *(const float4*)&lnb[layer * 128 + c];
    }

    const int NT = (NN + 31) / 32;
    const int myrow = rt_w * 16 + lr;
    for (int tile = blockIdx.x; tile < NT; tile += gridDim.x) {
        const int row0 = tile * 32;
        const int node = row0 + myrow;

        // residual prefetch
        uint2 hres[2] = {{0u, 0u}, {0u, 0u}};
        if (node < NN) {
            #pragma unroll
            for (int nt = 0; nt < 2; ++nt)
                hres[nt] = *(const uint2*)&h16i[((size_t)ch * NN + node) * 32 + nt * 16 + lk * 4];
        }

        // ---- phase 1: C1^T = W1(A) x z(B); z slice = kk exactly ----
        f32x4 acc1[2][2];
        #pragma unroll
        for (int nt = 0; nt < 2; ++nt)
            #pragma unroll
            for (int rt = 0; rt < 2; ++rt) acc1[nt][rt] = (f32x4){0.f, 0.f, 0.f, 0.f};
        #pragma unroll
        for (int kk = 0; kk < 4; ++kk) {
            bf16x8 bv[2];
            #pragma unroll
            for (int rt = 0; rt < 2; ++rt) {
                const int zrow = row0 + rt * 16 + lr;
                bv[rt] = (zrow < NN)
                    ? *(const bf16x8*)(z16 + ((size_t)kk * NN + zrow) * 32 + lk * 8)
                    : (bf16x8){0, 0, 0, 0, 0, 0, 0, 0};
            }
            #pragma unroll
            for (int nt = 0; nt < 2; ++nt)
                #pragma unroll
                for (int rt = 0; rt < 2; ++rt)
                    acc1[nt][rt] = __builtin_amdgcn_mfma_f32_16x16x32_bf16(fa1[nt][kk], bv[rt], acc1[nt][rt], 0, 0, 0);
        }
        // bias + relu -> ts (lane holds 4 consecutive n-cols at one z-row)
        #pragma unroll
        for (int nt = 0; nt < 2; ++nt) {
            const int nc = (w * 2 + nt) * 16 + lk * 4;
            #pragma unroll
            for (int rt = 0; rt < 2; ++rt) {
                const int zrow = rt * 16 + lr;
                unsigned lo = pk2(fmaxf(acc1[nt][rt][0] + bb1[nt].x, 0.f),
                                  fmaxf(acc1[nt][rt][1] + bb1[nt].y, 0.f));
                unsigned hi = pk2(fmaxf(acc1[nt][rt][2] + bb1[nt].z, 0.f),
                                  fmaxf(acc1[nt][rt][3] + bb1[nt].w, 0.f));
                const int byte = (zrow * 512 + nc * 2) ^ ((zrow & 7) << 4);
                uint2 o; o.x = lo; o.y = hi;
                *(uint2*)((char*)ts + byte) = o;
            }
        }
        __syncthreads();

        // ---- phase 2: C2^T = W2(A) x t(B); rows rt_w*16.., cols ch*32.. ----
        f32x4 acc2[2];
        acc2[0] = (f32x4){0.f, 0.f, 0.f, 0.f};
        acc2[1] = (f32x4){0.f, 0.f, 0.f, 0.f};
        #pragma unroll
        for (int kk = 0; kk < 8; ++kk) {
            const int byte = (myrow * 512 + kk * 64 + lk * 16) ^ ((myrow & 7) << 4);
            const bf16x8 bv = *(const bf16x8*)((const char*)ts + byte);
            acc2[0] = __builtin_amdgcn_mfma_f32_16x16x32_bf16(fa2[0][kk], bv, acc2[0], 0, 0, 0);
            acc2[1] = __builtin_amdgcn_mfma_f32_16x16x32_bf16(fa2[1][kk], bv, acc2[1], 0, 0, 0);
        }

        // ---- bias + residual + LN partials (lane: 8 cols of row `myrow`) ----
        float vals[2][4];
        float s = 0.f, ss = 0.f;
        #pragma unroll
        for (int nt = 0; nt < 2; ++nt) {
            float v0 = acc2[nt][0] + bb2[nt].x + bflo(hres[nt].x);
            float v1 = acc2[nt][1] + bb2[nt].y + bfhi(hres[nt].x);
            float v2 = acc2[nt][2] + bb2[nt].z + bflo(hres[nt].y);
            float v3 = acc2[nt][3] + bb2[nt].w + bfhi(hres[nt].y);
            vals[nt][0] = v0; vals[nt][1] = v1; vals[nt][2] = v2; vals[nt][3] = v3;
            s += v0 + v1 + v2 + v3;
            ss += v0 * v0 + v1 * v1 + v2 * v2 + v3 * v3;
        }
        s  += __shfl_xor(s, 16);  s  += __shfl_xor(s, 32);
        ss += __shfl_xor(ss, 16); ss += __shfl_xor(ss, 32);
        if (lk == 0) {
            red[rt_w][lr][ch][0] = s;
            red[rt_w][lr][ch][1] = ss;
        }
        __syncthreads();

        // cross-wave combine (4 col-slices per row)
        float st = red[rt_w][lr][0][0] + red[rt_w][lr][1][0] + red[rt_w][lr][2][0] + red[rt_w][lr][3][0];
        float sst = red[rt_w][lr][0][1] + red[rt_w][lr][1][1] + red[rt_w][lr][2][1] + red[rt_w][lr][3][1];
        const float mu = st * (1.f / 128.f);
        const float rstd = rsqrtf(sst * (1.f / 128.f) - mu * mu + 1e-5f);
        if (node < NN) {
            #pragma unroll
            for (int nt = 0; nt < 2; ++nt) {
                float o0 = (vals[nt][0] - mu) * rstd * g4[nt].x + be4[nt].x;
                float o1 = (vals[nt][1] - mu) * rstd * g4[nt].y + be4[nt].y;
                float o2 = (vals[nt][2] - mu) * rstd * g4[nt].z + be4[nt].z;
                float o3 = (vals[nt][3] - mu) * rstd * g4[nt].w + be4[nt].w;
                uint2 pkd; pkd.x = pk2(o0, o1); pkd.y = pk2(o2, o3);
                *(uint2*)&h16o[((size_t)ch * NN + node) * 32 + nt * 16 + lk * 4] = pkd;
            }
        }
    }
}

// ---------------- readout: out = h[roots] @ W_out (sliced h) ----------------
__global__ void __launch_bounds__(256) k_out(const ushort_t* __restrict__ h,
                                             const int* __restrict__ roots,
                                             const float* __restrict__ Wo,
                                             float* __restrict__ out) {
    __shared__ float hs[16 * 128];
    int t = threadIdx.x;
    int r0 = blockIdx.x * 16;
    for (int i = t; i < 16 * 32; i += 256) {
        int row = i >> 5, u = i & 31;
        const int sl = u >> 3, off = (u & 7) * 4;
        uint2 v = *(const uint2*)&h[((size_t)sl * NN + roots[r0 + row]) * 32 + off];
        hs[row * 128 + u * 4 + 0] = bflo(v.x);
        hs[row * 128 + u * 4 + 1] = bfhi(v.x);
        hs[row * 128 + u * 4 + 2] = bflo(v.y);
        hs[row * 128 + u * 4 + 3] = bfhi(v.y);
    }
    __syncthreads();
    for (int o = t; o < 16 * NO; o += 256) {
        int j = o / NO, c = o % NO;
        float s = 0.f;
        for (int k = 0; k < 128; ++k) s += hs[j * 128 + k] * Wo[k * NO + c];
        out[(r0 + j) * NO + c] = s;
    }
}

extern "C" void kernel_launch(void* const* d_in, const int* in_sizes, int n_in,
                              void* d_out, int out_size, void* d_ws, size_t ws_size,
                              hipStream_t stream) {
    const int*   x    = (const int*)d_in[0];
    const int*   ei   = (const int*)d_in[1];
    const int*   roots= (const int*)d_in[2];
    const float* ke   = (const float*)d_in[3];
    const float* ve   = (const float*)d_in[4];
    const float* eps  = (const float*)d_in[5];
    const float* W1   = (const float*)d_in[6];
    const float* b1   = (const float*)d_in[7];
    const float* W2   = (const float*)d_in[8];
    const float* b2   = (const float*)d_in[9];
    const float* g    = (const float*)d_in[10];
    const float* bt   = (const float*)d_in[11];
    const float* Wo   = (const float*)d_in[12];
    float* out = (float*)d_out;

    char* ws = (char*)d_ws;
    size_t off = 0;
    auto alloc = [&](size_t bytes) {
        void* p = ws + off;
        off += (bytes + 255) & ~(size_t)255;
        return p;
    };
    ushort_t* h16A = (ushort_t*)alloc((size_t)NN * D * 2);
    ushort_t* h16B = (ushort_t*)alloc((size_t)NN * D * 2);
    ushort_t* z16  = (ushort_t*)alloc((size_t)NN * D * 2);
    ushort_t* W1tb = (ushort_t*)alloc((size_t)NL * 256 * 128 * 2);
    ushort_t* W2tb = (ushort_t*)alloc((size_t)NL * 128 * 256 * 2);
    int* deg  = (int*)alloc((size_t)NN * 4);
    int* incl = (int*)alloc((size_t)NN * 4);
    int* bsum = (int*)alloc(256 * 4);
    int* rs   = (int*)alloc((size_t)(NN + 1) * 4);
    int* cur  = (int*)alloc((size_t)NN * 4);
    ushort_t* csrc = (ushort_t*)alloc((size_t)NE * 2);

    hipMemsetAsync(deg, 0, (size_t)NN * 4, stream);

    const int initTot = NN * 32 + 2 * NL * 32768 + NE;
    k_initw<<<(initTot + 255) / 256, 256, 0, stream>>>(x, ke, ve, h16A, W1, W1tb, W2, W2tb, ei, deg);
    int nb = (NN + 255) / 256;
    k_scan1<<<nb, 256, 0, stream>>>(deg, incl, bsum);
    k_scan2<<<1, 256, 0, stream>>>(bsum, nb);
    k_scan3<<<nb, 256, 0, stream>>>(deg, incl, bsum, rs, cur);
    k_fill<<<FILL_NB, 256, 0, stream>>>(ei, cur, csrc);

    const int aggBlocks = (NN / 16) * 4;   // 3125 node-blocks x 4 slices
    for (int l = 0; l < NL; ++l) {
        const ushort_t* hi = (l & 1) ? h16B : h16A;
        ushort_t*       ho = (l & 1) ? h16A : h16B;
        k_agg<<<aggBlocks, 256, 0, stream>>>(hi, rs, csrc, eps, l, z16);
        k_mlp<<<512, 512, 0, stream>>>(z16, hi, ho, l, W1tb, b1, W2tb, b2, g, bt);
    }
    k_out<<<NR / 16, 256, 0, stream>>>(h16B, roots, Wo, out);
}

// Round 17
// 396.762 us; speedup vs baseline: 1.4791x; 1.0532x over previous
//
#include <hip/hip_runtime.h>
#include <hip/hip_bf16.h>

#define NN 50000
#define NE 800000
#define D 128
#define NL 5
#define NR 2048
#define NO 65
#define FILL_NB 1024

typedef unsigned short ushort_t;
typedef __attribute__((ext_vector_type(8))) short bf16x8;
typedef __attribute__((ext_vector_type(4))) float f32x4;

// h16/z16 stored SLICE-MAJOR: [4][NN][32] bf16 — dim d of node n lives at
// ((d>>5)*NN + n)*32 + (d&31). One 32-dim slice per XCD-pinned gather block.

__device__ inline float bflo(unsigned u) {
    return __builtin_bit_cast(float, u << 16);
}
__device__ inline float bfhi(unsigned u) {
    return __builtin_bit_cast(float, u & 0xFFFF0000u);
}
__device__ inline ushort_t f2bf(float f) {
    unsigned u = __builtin_bit_cast(unsigned, f);
    u = (u + 0x7FFF + ((u >> 16) & 1)) >> 16;   // RNE
    return (ushort_t)u;
}
__device__ inline unsigned pk2(float a, float b) {
    return (unsigned)f2bf(a) | ((unsigned)f2bf(b) << 16);
}
__device__ inline void acc8(float* a, uint4 v) {
    a[0] += bflo(v.x); a[1] += bfhi(v.x);
    a[2] += bflo(v.y); a[3] += bfhi(v.y);
    a[4] += bflo(v.z); a[5] += bfhi(v.z);
    a[6] += bflo(v.w); a[7] += bfhi(v.w);
}

// ------ combined init: h0 (sliced bf16) + W1t/W2t transpose-convert ------
__global__ void k_initw(const int* __restrict__ x, const float* __restrict__ ke,
                        const float* __restrict__ ve, ushort_t* __restrict__ h16,
                        const float* __restrict__ W1, ushort_t* __restrict__ W1t,
                        const float* __restrict__ W2, ushort_t* __restrict__ W2t) {
    int i = blockIdx.x * blockDim.x + threadIdx.x;
    if (i < NN * 32) {
        int node = i >> 5, f4 = (i & 31) * 4;
        float4 a = *(const float4*)&ke[(size_t)x[node * 2 + 0] * D + f4];
        float4 b = *(const float4*)&ve[(size_t)x[node * 2 + 1] * D + f4];
        uint2 o;
        o.x = pk2(a.x + b.x, a.y + b.y);
        o.y = pk2(a.z + b.z, a.w + b.w);
        const int s = f4 >> 5, off = f4 & 31;
        *(uint2*)&h16[((size_t)s * NN + node) * 32 + off] = o;
        return;
    }
    int j = i - NN * 32;
    if (j < NL * 32768) {               // W1t[l][n(256)][k(128)]
        int l = j / 32768, r = j % 32768;
        int n = r >> 7, k = r & 127;
        W1t[j] = f2bf(W1[l * 32768 + k * 256 + n]);
        return;
    }
    j -= NL * 32768;
    if (j < NL * 32768) {               // W2t[l][n(128)][k(256)]
        int l = j / 32768, r = j % 32768;
        int n = r >> 8, k = r & 255;
        W2t[j] = f2bf(W2[l * 32768 + k * 128 + n]);
    }
}

// XCD-partitioned histogram: block b serves dst-partition b&7 — deg lines are
// dirtied in exactly one XCD's L2 (no cross-XCD atomic line bouncing).
__global__ void k_hist(const int* __restrict__ ei, int* __restrict__ deg) {
    const int part = blockIdx.x & 7;
    const int j = blockIdx.x >> 3;
    const int lo = part * (NN / 8), hi = lo + (NN / 8);
    for (int e = j * 256 + threadIdx.x; e < NE; e += (FILL_NB / 8) * 256) {
        const int d = ei[NE + e];
        if (d >= lo && d < hi) atomicAdd(&deg[d], 1);
    }
}

__global__ void k_scan1(const int* __restrict__ deg, int* __restrict__ incl,
                        int* __restrict__ bsums) {
    __shared__ int s[256];
    int t = threadIdx.x, i = blockIdx.x * 256 + t;
    int v = (i < NN) ? deg[i] : 0;
    s[t] = v; __syncthreads();
    for (int off = 1; off < 256; off <<= 1) {
        int u = (t >= off) ? s[t - off] : 0;
        __syncthreads();
        s[t] += u; __syncthreads();
    }
    if (i < NN) incl[i] = s[t];
    if (t == 255) bsums[blockIdx.x] = s[255];
}

__global__ void k_scan2(int* __restrict__ bsums, int nb) {
    __shared__ int s[256];
    int t = threadIdx.x;
    int v = (t < nb) ? bsums[t] : 0;
    s[t] = v; __syncthreads();
    for (int off = 1; off < 256; off <<= 1) {
        int u = (t >= off) ? s[t - off] : 0;
        __syncthreads();
        s[t] += u; __syncthreads();
    }
    if (t < nb) bsums[t] = s[t] - v;   // exclusive
}

__global__ void k_scan3(const int* __restrict__ deg, const int* __restrict__ incl,
                        const int* __restrict__ bsums, int* __restrict__ rs,
                        int* __restrict__ cur) {
    int i = blockIdx.x * blockDim.x + threadIdx.x;
    if (i >= NN) return;
    int ex = incl[i] - deg[i] + bsums[i >> 8];
    rs[i] = ex; cur[i] = ex;
    if (i == 0) rs[NN] = NE;
}

// XCD-partitioned fill: block b serves dst-partition b&7 (6250 nodes);
// csrc/cur lines for a partition are dirtied in exactly one XCD's L2.
__global__ void k_fill(const int* __restrict__ ei, int* __restrict__ cur,
                       ushort_t* __restrict__ csrc) {
    const int part = blockIdx.x & 7;
    const int j = blockIdx.x >> 3;
    const int lo = part * (NN / 8), hi = lo + (NN / 8);
    for (int e = j * 256 + threadIdx.x; e < NE; e += (FILL_NB / 8) * 256) {
        const int d = ei[NE + e];
        if (d >= lo && d < hi) {
            const int pos = atomicAdd(&cur[d], 1);
            csrc[pos] = (ushort_t)ei[e];    // src < 50000 < 65536
        }
    }
}

// ------- aggregate (sliced): z16[s] = bf16((1+eps)*h[s] + sum_in h[s][src]) -----
// block = 256 thr = 4 waves, 16 nodes x ONE 32-dim slice (blockIdx&3; XCD-pinned).
// wave: 4 nodes (grp), 4 edge-phases (q) x batch-4 = 16 edges/node in flight,
// 4 lanes per 64B slice row (p). Proven R13 shape.
__global__ void __launch_bounds__(256) k_agg(const ushort_t* __restrict__ h16,
                                             const int* __restrict__ rs,
                                             const ushort_t* __restrict__ csrc,
                                             const float* __restrict__ epsArr, int layer,
                                             ushort_t* __restrict__ z16) {
    const int s = blockIdx.x & 3;
    const int nb = blockIdx.x >> 2;
    const int wv = threadIdx.x >> 6;
    const int lane = threadIdx.x & 63;
    const int grp = lane >> 4;            // which of the wave's 4 nodes
    const int q = (lane >> 2) & 3;        // edge phase (4)
    const int p = lane & 3;               // which uint4 of the 64B slice row
    const int node = nb * 16 + wv * 4 + grp;    // 3125*16 == NN exactly
    const uint4* H4 = (const uint4*)(h16 + (size_t)s * NN * 32);
    const int myE0 = rs[node], myE1 = rs[node + 1];
    const uint4 own = H4[(size_t)node * 4 + p];
    float acc[8] = {0.f, 0.f, 0.f, 0.f, 0.f, 0.f, 0.f, 0.f};
    for (int e = myE0 + q; e < myE1; e += 16) {
        const int ia = csrc[e];
        const int e1 = e + 4, e2 = e + 8, e3 = e + 12;
        const int ib = (e1 < myE1) ? (int)csrc[e1] : -1;
        const int ic = (e2 < myE1) ? (int)csrc[e2] : -1;
        const int id = (e3 < myE1) ? (int)csrc[e3] : -1;
        acc8(acc, H4[(size_t)ia * 4 + p]);
        if (ib >= 0) acc8(acc, H4[(size_t)ib * 4 + p]);
        if (ic >= 0) acc8(acc, H4[(size_t)ic * 4 + p]);
        if (id >= 0) acc8(acc, H4[(size_t)id * 4 + p]);
    }
    #pragma unroll
    for (int k = 0; k < 8; ++k) {         // reduce over q bits (4,8); grp,p kept
        acc[k] += __shfl_xor(acc[k], 4);
        acc[k] += __shfl_xor(acc[k], 8);
    }
    if (q == 0) {
        const float epsl = 1.f + epsArr[layer];
        float r0 = acc[0] + epsl * bflo(own.x), r1 = acc[1] + epsl * bfhi(own.x);
        float r2 = acc[2] + epsl * bflo(own.y), r3 = acc[3] + epsl * bfhi(own.y);
        float r4 = acc[4] + epsl * bflo(own.z), r5 = acc[5] + epsl * bfhi(own.z);
        float r6 = acc[6] + epsl * bflo(own.w), r7 = acc[7] + epsl * bfhi(own.w);
        uint4 o;
        o.x = pk2(r0, r1); o.y = pk2(r2, r3);
        o.z = pk2(r4, r5); o.w = pk2(r6, r7);
        ((uint4*)(z16 + (size_t)s * NN * 32))[(size_t)node * 4 + p] = o;
    }
}

// ============ persistent MFMA MLP + residual + LayerNorm (sliced I/O) ============
__global__ void __launch_bounds__(512, 2) k_mlp(
        const ushort_t* __restrict__ z16,
        const ushort_t* __restrict__ h16i, ushort_t* __restrict__ h16o,
        const int layer,
        const ushort_t* __restrict__ W1t, const float* __restrict__ b1,
        const ushort_t* __restrict__ W2t, const float* __restrict__ b2,
        const float* __restrict__ lng, const float* __restrict__ lnb) {
    __shared__ ushort_t ts[32 * 256];        // 16 KB, XOR-swizzled (512 B rows)
    __shared__ float red[2][16][4][2];       // cross-wave LN partials
    const int t = threadIdx.x;
    const int lane = t & 63, w = t >> 6;     // 8 waves
    const int lr = lane & 15, lk = lane >> 4;
    const int rt_w = w & 1, ch = w >> 1;     // ch = col-slice (0..3)

    // ---- register-cache weight fragments (once per block) ----
    const ushort_t* W1p = W1t + (size_t)layer * 256 * 128;
    const ushort_t* W2p = W2t + (size_t)layer * 128 * 256;
    bf16x8 fa1[2][4];
    #pragma unroll
    for (int nt = 0; nt < 2; ++nt)
        #pragma unroll
        for (int kk = 0; kk < 4; ++kk)
            fa1[nt][kk] = *(const bf16x8*)(W1p + (size_t)((w * 2 + nt) * 16 + lr) * 128 + kk * 32 + lk * 8);
    bf16x8 fa2[2][8];
    #pragma unroll
    for (int nt = 0; nt < 2; ++nt)
        #pragma unroll
        for (int kk = 0; kk < 8; ++kk)
            fa2[nt][kk] = *(const bf16x8*)(W2p + (size_t)((ch * 2 + nt) * 16 + lr) * 256 + kk * 32 + lk * 8);

    // per-lane bias/LN params (fixed columns)
    float4 bb1[2], bb2[2], g4[2], be4[2];
    #pragma unroll
    for (int nt = 0; nt < 2; ++nt) {
        bb1[nt] = *(const float4*)&b1[layer * 256 + (w * 2 + nt) * 16 + lk * 4];
        const int c = (ch * 2 + nt) * 16 + lk * 4;
        bb2[nt] = *(const float4*)&b2[layer * 128 + c];
        g4[nt]  = *(const float4*)&lng[layer * 128 + c];
        be4[nt] = *(const float4*)&lnb[layer * 128 + c];
    }

    const int NT = (NN + 31) / 32;
    const int myrow = rt_w * 16 + lr;
    for (int tile = blockIdx.x; tile < NT; tile += gridDim.x) {
        const int row0 = tile * 32;
        const int node = row0 + myrow;

        // residual prefetch
        uint2 hres[2] = {{0u, 0u}, {0u, 0u}};
        if (node < NN) {
            #pragma unroll
            for (int nt = 0; nt < 2; ++nt)
                hres[nt] = *(const uint2*)&h16i[((size_t)ch * NN + node) * 32 + nt * 16 + lk * 4];
        }

        // ---- phase 1: C1^T = W1(A) x z(B); z slice = kk exactly ----
        f32x4 acc1[2][2];
        #pragma unroll
        for (int nt = 0; nt < 2; ++nt)
            #pragma unroll
            for (int rt = 0; rt < 2; ++rt) acc1[nt][rt] = (f32x4){0.f, 0.f, 0.f, 0.f};
        #pragma unroll
        for (int kk = 0; kk < 4; ++kk) {
            bf16x8 bv[2];
            #pragma unroll
            for (int rt = 0; rt < 2; ++rt) {
                const int zrow = row0 + rt * 16 + lr;
                bv[rt] = (zrow < NN)
                    ? *(const bf16x8*)(z16 + ((size_t)kk * NN + zrow) * 32 + lk * 8)
                    : (bf16x8){0, 0, 0, 0, 0, 0, 0, 0};
            }
            #pragma unroll
            for (int nt = 0; nt < 2; ++nt)
                #pragma unroll
                for (int rt = 0; rt < 2; ++rt)
                    acc1[nt][rt] = __builtin_amdgcn_mfma_f32_16x16x32_bf16(fa1[nt][kk], bv[rt], acc1[nt][rt], 0, 0, 0);
        }
        // bias + relu -> ts (lane holds 4 consecutive n-cols at one z-row)
        #pragma unroll
        for (int nt = 0; nt < 2; ++nt) {
            const int nc = (w * 2 + nt) * 16 + lk * 4;
            #pragma unroll
            for (int rt = 0; rt < 2; ++rt) {
                const int zrow = rt * 16 + lr;
                unsigned lo = pk2(fmaxf(acc1[nt][rt][0] + bb1[nt].x, 0.f),
                                  fmaxf(acc1[nt][rt][1] + bb1[nt].y, 0.f));
                unsigned hi = pk2(fmaxf(acc1[nt][rt][2] + bb1[nt].z, 0.f),
                                  fmaxf(acc1[nt][rt][3] + bb1[nt].w, 0.f));
                const int byte = (zrow * 512 + nc * 2) ^ ((zrow & 7) << 4);
                uint2 o; o.x = lo; o.y = hi;
                *(uint2*)((char*)ts + byte) = o;
            }
        }
        __syncthreads();

        // ---- phase 2: C2^T = W2(A) x t(B); rows rt_w*16.., cols ch*32.. ----
        f32x4 acc2[2];
        acc2[0] = (f32x4){0.f, 0.f, 0.f, 0.f};
        acc2[1] = (f32x4){0.f, 0.f, 0.f, 0.f};
        #pragma unroll
        for (int kk = 0; kk < 8; ++kk) {
            const int byte = (myrow * 512 + kk * 64 + lk * 16) ^ ((myrow & 7) << 4);
            const bf16x8 bv = *(const bf16x8*)((const char*)ts + byte);
            acc2[0] = __builtin_amdgcn_mfma_f32_16x16x32_bf16(fa2[0][kk], bv, acc2[0], 0, 0, 0);
            acc2[1] = __builtin_amdgcn_mfma_f32_16x16x32_bf16(fa2[1][kk], bv, acc2[1], 0, 0, 0);
        }

        // ---- bias + residual + LN partials (lane: 8 cols of row `myrow`) ----
        float vals[2][4];
        float s = 0.f, ss = 0.f;
        #pragma unroll
        for (int nt = 0; nt < 2; ++nt) {
            float v0 = acc2[nt][0] + bb2[nt].x + bflo(hres[nt].x);
            float v1 = acc2[nt][1] + bb2[nt].y + bfhi(hres[nt].x);
            float v2 = acc2[nt][2] + bb2[nt].z + bflo(hres[nt].y);
            float v3 = acc2[nt][3] + bb2[nt].w + bfhi(hres[nt].y);
            vals[nt][0] = v0; vals[nt][1] = v1; vals[nt][2] = v2; vals[nt][3] = v3;
            s += v0 + v1 + v2 + v3;
            ss += v0 * v0 + v1 * v1 + v2 * v2 + v3 * v3;
        }
        s  += __shfl_xor(s, 16);  s  += __shfl_xor(s, 32);
        ss += __shfl_xor(ss, 16); ss += __shfl_xor(ss, 32);
        if (lk == 0) {
            red[rt_w][lr][ch][0] = s;
            red[rt_w][lr][ch][1] = ss;
        }
        __syncthreads();

        // cross-wave combine (4 col-slices per row)
        float st = red[rt_w][lr][0][0] + red[rt_w][lr][1][0] + red[rt_w][lr][2][0] + red[rt_w][lr][3][0];
        float sst = red[rt_w][lr][0][1] + red[rt_w][lr][1][1] + red[rt_w][lr][2][1] + red[rt_w][lr][3][1];
        const float mu = st * (1.f / 128.f);
        const float rstd = rsqrtf(sst * (1.f / 128.f) - mu * mu + 1e-5f);
        if (node < NN) {
            #pragma unroll
            for (int nt = 0; nt < 2; ++nt) {
                float o0 = (vals[nt][0] - mu) * rstd * g4[nt].x + be4[nt].x;
                float o1 = (vals[nt][1] - mu) * rstd * g4[nt].y + be4[nt].y;
                float o2 = (vals[nt][2] - mu) * rstd * g4[nt].z + be4[nt].z;
                float o3 = (vals[nt][3] - mu) * rstd * g4[nt].w + be4[nt].w;
                uint2 pkd; pkd.x = pk2(o0, o1); pkd.y = pk2(o2, o3);
                *(uint2*)&h16o[((size_t)ch * NN + node) * 32 + nt * 16 + lk * 4] = pkd;
            }
        }
    }
}

// ---------------- readout: out = h[roots] @ W_out (sliced h) ----------------
__global__ void __launch_bounds__(256) k_out(const ushort_t* __restrict__ h,
                                             const int* __restrict__ roots,
                                             const float* __restrict__ Wo,
                                             float* __restrict__ out) {
    __shared__ float hs[16 * 128];
    int t = threadIdx.x;
    int r0 = blockIdx.x * 16;
    for (int i = t; i < 16 * 32; i += 256) {
        int row = i >> 5, u = i & 31;
        const int sl = u >> 3, off = (u & 7) * 4;
        uint2 v = *(const uint2*)&h[((size_t)sl * NN + roots[r0 + row]) * 32 + off];
        hs[row * 128 + u * 4 + 0] = bflo(v.x);
        hs[row * 128 + u * 4 + 1] = bfhi(v.x);
        hs[row * 128 + u * 4 + 2] = bflo(v.y);
        hs[row * 128 + u * 4 + 3] = bfhi(v.y);
    }
    __syncthreads();
    for (int o = t; o < 16 * NO; o += 256) {
        int j = o / NO, c = o % NO;
        float s = 0.f;
        for (int k = 0; k < 128; ++k) s += hs[j * 128 + k] * Wo[k * NO + c];
        out[(r0 + j) * NO + c] = s;
    }
}

extern "C" void kernel_launch(void* const* d_in, const int* in_sizes, int n_in,
                              void* d_out, int out_size, void* d_ws, size_t ws_size,
                              hipStream_t stream) {
    const int*   x    = (const int*)d_in[0];
    const int*   ei   = (const int*)d_in[1];
    const int*   roots= (const int*)d_in[2];
    const float* ke   = (const float*)d_in[3];
    const float* ve   = (const float*)d_in[4];
    const float* eps  = (const float*)d_in[5];
    const float* W1   = (const float*)d_in[6];
    const float* b1   = (const float*)d_in[7];
    const float* W2   = (const float*)d_in[8];
    const float* b2   = (const float*)d_in[9];
    const float* g    = (const float*)d_in[10];
    const float* bt   = (const float*)d_in[11];
    const float* Wo   = (const float*)d_in[12];
    float* out = (float*)d_out;

    char* ws = (char*)d_ws;
    size_t off = 0;
    auto alloc = [&](size_t bytes) {
        void* p = ws + off;
        off += (bytes + 255) & ~(size_t)255;
        return p;
    };
    ushort_t* h16A = (ushort_t*)alloc((size_t)NN * D * 2);
    ushort_t* h16B = (ushort_t*)alloc((size_t)NN * D * 2);
    ushort_t* z16  = (ushort_t*)alloc((size_t)NN * D * 2);
    ushort_t* W1tb = (ushort_t*)alloc((size_t)NL * 256 * 128 * 2);
    ushort_t* W2tb = (ushort_t*)alloc((size_t)NL * 128 * 256 * 2);
    int* deg  = (int*)alloc((size_t)NN * 4);
    int* incl = (int*)alloc((size_t)NN * 4);
    int* bsum = (int*)alloc(256 * 4);
    int* rs   = (int*)alloc((size_t)(NN + 1) * 4);
    int* cur  = (int*)alloc((size_t)NN * 4);
    ushort_t* csrc = (ushort_t*)alloc((size_t)NE * 2);

    hipMemsetAsync(deg, 0, (size_t)NN * 4, stream);

    const int initTot = NN * 32 + 2 * NL * 32768;
    k_initw<<<(initTot + 255) / 256, 256, 0, stream>>>(x, ke, ve, h16A, W1, W1tb, W2, W2tb);
    k_hist<<<FILL_NB, 256, 0, stream>>>(ei, deg);
    int nb = (NN + 255) / 256;
    k_scan1<<<nb, 256, 0, stream>>>(deg, incl, bsum);
    k_scan2<<<1, 256, 0, stream>>>(bsum, nb);
    k_scan3<<<nb, 256, 0, stream>>>(deg, incl, bsum, rs, cur);
    k_fill<<<FILL_NB, 256, 0, stream>>>(ei, cur, csrc);

    const int aggBlocks = (NN / 16) * 4;   // 3125 node-blocks x 4 slices
    for (int l = 0; l < NL; ++l) {
        const ushort_t* hi = (l & 1) ? h16B : h16A;
        ushort_t*       ho = (l & 1) ? h16A : h16B;
        k_agg<<<aggBlocks, 256, 0, stream>>>(hi, rs, csrc, eps, l, z16);
        k_mlp<<<256, 512, 0, stream>>>(z16, hi, ho, l, W1tb, b1, W2tb, b2, g, bt);
    }
    k_out<<<NR / 16, 256, 0, stream>>>(h16B, roots, Wo, out);
}

// Round 18
// 385.300 us; speedup vs baseline: 1.5231x; 1.0297x over previous
//
#include <hip/hip_runtime.h>
#include <hip/hip_bf16.h>

#define NN 50000
#define NN1 50001                 // +1 zero-node row (gather padding target)
#define NE 800000
#define D 128
#define NL 5
#define NR 2048
#define NO 65
#define FILL_NB 1024

typedef unsigned short ushort_t;
typedef __attribute__((ext_vector_type(8))) short bf16x8;
typedef __attribute__((ext_vector_type(4))) float f32x4;

// h16/z16 stored SLICE-MAJOR: [4][NN1][32] bf16 — dim d of node n lives at
// ((d>>5)*NN1 + n)*32 + (d&31). Row NN is all-zero (padding target).

__device__ inline float bflo(unsigned u) {
    return __builtin_bit_cast(float, u << 16);
}
__device__ inline float bfhi(unsigned u) {
    return __builtin_bit_cast(float, u & 0xFFFF0000u);
}
__device__ inline ushort_t f2bf(float f) {
    unsigned u = __builtin_bit_cast(unsigned, f);
    u = (u + 0x7FFF + ((u >> 16) & 1)) >> 16;   // RNE
    return (ushort_t)u;
}
__device__ inline unsigned pk2(float a, float b) {
    return (unsigned)f2bf(a) | ((unsigned)f2bf(b) << 16);
}
__device__ inline void acc8(float* a, uint4 v) {
    a[0] += bflo(v.x); a[1] += bfhi(v.x);
    a[2] += bflo(v.y); a[3] += bfhi(v.y);
    a[4] += bflo(v.z); a[5] += bfhi(v.z);
    a[6] += bflo(v.w); a[7] += bfhi(v.w);
}

// ------ combined init: h0 (sliced bf16) + W1t/W2t transpose + zero rows ------
__global__ void k_initw(const int* __restrict__ x, const float* __restrict__ ke,
                        const float* __restrict__ ve, ushort_t* __restrict__ h16A,
                        ushort_t* __restrict__ h16B,
                        const float* __restrict__ W1, ushort_t* __restrict__ W1t,
                        const float* __restrict__ W2, ushort_t* __restrict__ W2t) {
    int i = blockIdx.x * blockDim.x + threadIdx.x;
    if (i < NN * 32) {
        int node = i >> 5, f4 = (i & 31) * 4;
        float4 a = *(const float4*)&ke[(size_t)x[node * 2 + 0] * D + f4];
        float4 b = *(const float4*)&ve[(size_t)x[node * 2 + 1] * D + f4];
        uint2 o;
        o.x = pk2(a.x + b.x, a.y + b.y);
        o.y = pk2(a.z + b.z, a.w + b.w);
        const int s = f4 >> 5, off = f4 & 31;
        *(uint2*)&h16A[((size_t)s * NN1 + node) * 32 + off] = o;
        return;
    }
    int j = i - NN * 32;
    if (j < NL * 32768) {               // W1t[l][n(256)][k(128)]
        int l = j / 32768, r = j % 32768;
        int n = r >> 7, k = r & 127;
        W1t[j] = f2bf(W1[l * 32768 + k * 256 + n]);
        return;
    }
    j -= NL * 32768;
    if (j < NL * 32768) {               // W2t[l][n(128)][k(256)]
        int l = j / 32768, r = j % 32768;
        int n = r >> 8, k = r & 255;
        W2t[j] = f2bf(W2[l * 32768 + k * 128 + n]);
        return;
    }
    j -= NL * 32768;
    if (j < 64) {                       // zero rows (node NN) for both buffers
        ushort_t* buf = (j >> 5) ? h16B : h16A;
        const int r = j & 31;
        const int s = r >> 3, off = (r & 7) * 4;
        uint2 z = {0u, 0u};
        *(uint2*)&buf[((size_t)s * NN1 + NN) * 32 + off] = z;
    }
}

// XCD-partitioned histogram: block b serves dst-partition b&7.
__global__ void k_hist(const int* __restrict__ ei, int* __restrict__ deg) {
    const int part = blockIdx.x & 7;
    const int j = blockIdx.x >> 3;
    const int lo = part * (NN / 8), hi = lo + (NN / 8);
    for (int e = j * 256 + threadIdx.x; e < NE; e += (FILL_NB / 8) * 256) {
        const int d = ei[NE + e];
        if (d >= lo && d < hi) atomicAdd(&deg[d], 1);
    }
}

// scans operate on PADDED degrees: pdeg = (deg+15)&~15
__global__ void k_scan1(const int* __restrict__ deg, int* __restrict__ incl,
                        int* __restrict__ bsums) {
    __shared__ int s[256];
    int t = threadIdx.x, i = blockIdx.x * 256 + t;
    int v = (i < NN) ? ((deg[i] + 15) & ~15) : 0;
    s[t] = v; __syncthreads();
    for (int off = 1; off < 256; off <<= 1) {
        int u = (t >= off) ? s[t - off] : 0;
        __syncthreads();
        s[t] += u; __syncthreads();
    }
    if (i < NN) incl[i] = s[t];
    if (t == 255) bsums[blockIdx.x] = s[255];
}

__global__ void k_scan2(int* __restrict__ bsums, int nb) {
    __shared__ int s[256];
    int t = threadIdx.x;
    int v = (t < nb) ? bsums[t] : 0;
    s[t] = v; __syncthreads();
    for (int off = 1; off < 256; off <<= 1) {
        int u = (t >= off) ? s[t - off] : 0;
        __syncthreads();
        s[t] += u; __syncthreads();
    }
    if (t < nb) bsums[t] = s[t] - v;   // exclusive
}

// rs = padded starts; also writes the zero-node filler indices into the pad
// region [rs+deg, rs+pdeg) so the gather loop needs no bounds checks.
__global__ void k_scan3(const int* __restrict__ deg, const int* __restrict__ incl,
                        const int* __restrict__ bsums, int* __restrict__ rs,
                        int* __restrict__ cur, ushort_t* __restrict__ csrc) {
    int i = blockIdx.x * blockDim.x + threadIdx.x;
    if (i >= NN) return;
    const int d = deg[i];
    const int pd = (d + 15) & ~15;
    int ex = incl[i] - pd + bsums[i >> 8];
    rs[i] = ex; cur[i] = ex;
    for (int j = ex + d; j < ex + pd; ++j) csrc[j] = (ushort_t)NN;
    if (i == NN - 1) rs[NN] = ex + pd;
}

// XCD-partitioned fill (writes real edges; pad slots pre-filled by k_scan3).
__global__ void k_fill(const int* __restrict__ ei, int* __restrict__ cur,
                       ushort_t* __restrict__ csrc) {
    const int part = blockIdx.x & 7;
    const int j = blockIdx.x >> 3;
    const int lo = part * (NN / 8), hi = lo + (NN / 8);
    for (int e = j * 256 + threadIdx.x; e < NE; e += (FILL_NB / 8) * 256) {
        const int d = ei[NE + e];
        if (d >= lo && d < hi) {
            const int pos = atomicAdd(&cur[d], 1);
            csrc[pos] = (ushort_t)ei[e];    // src < 50000 < 65536
        }
    }
}

// ------- aggregate (sliced): z16[s] = bf16((1+eps)*h[s] + sum_in h[s][src]) -----
// block = 256 thr = 4 waves, 16 nodes x ONE 32-dim slice (blockIdx&3; XCD-pinned).
// wave: 4 nodes (grp), 4 edge-phases (q) x batch-4; padded CSR -> NO bounds checks.
__global__ void __launch_bounds__(256) k_agg(const ushort_t* __restrict__ h16,
                                             const int* __restrict__ rs,
                                             const ushort_t* __restrict__ csrc,
                                             const float* __restrict__ epsArr, int layer,
                                             ushort_t* __restrict__ z16) {
    const int s = blockIdx.x & 3;
    const int nb = blockIdx.x >> 2;
    const int wv = threadIdx.x >> 6;
    const int lane = threadIdx.x & 63;
    const int grp = lane >> 4;            // which of the wave's 4 nodes
    const int q = (lane >> 2) & 3;        // edge phase (4)
    const int p = lane & 3;               // which uint4 of the 64B slice row
    const int node = nb * 16 + wv * 4 + grp;    // 3125*16 == NN exactly
    const uint4* H4 = (const uint4*)(h16 + (size_t)s * NN1 * 32);
    const int myE0 = rs[node], myE1 = rs[node + 1];   // padded: multiple of 16
    const uint4 own = H4[(size_t)node * 4 + p];
    float acc[8] = {0.f, 0.f, 0.f, 0.f, 0.f, 0.f, 0.f, 0.f};
    for (int e = myE0 + q; e < myE1; e += 16) {
        const int ia = csrc[e];
        const int ib = csrc[e + 4];
        const int ic = csrc[e + 8];
        const int id = csrc[e + 12];
        acc8(acc, H4[(size_t)ia * 4 + p]);
        acc8(acc, H4[(size_t)ib * 4 + p]);
        acc8(acc, H4[(size_t)ic * 4 + p]);
        acc8(acc, H4[(size_t)id * 4 + p]);
    }
    #pragma unroll
    for (int k = 0; k < 8; ++k) {         // reduce over q bits (4,8); grp,p kept
        acc[k] += __shfl_xor(acc[k], 4);
        acc[k] += __shfl_xor(acc[k], 8);
    }
    if (q == 0) {
        const float epsl = 1.f + epsArr[layer];
        float r0 = acc[0] + epsl * bflo(own.x), r1 = acc[1] + epsl * bfhi(own.x);
        float r2 = acc[2] + epsl * bflo(own.y), r3 = acc[3] + epsl * bfhi(own.y);
        float r4 = acc[4] + epsl * bflo(own.z), r5 = acc[5] + epsl * bfhi(own.z);
        float r6 = acc[6] + epsl * bflo(own.w), r7 = acc[7] + epsl * bfhi(own.w);
        uint4 o;
        o.x = pk2(r0, r1); o.y = pk2(r2, r3);
        o.z = pk2(r4, r5); o.w = pk2(r6, r7);
        ((uint4*)(z16 + (size_t)s * NN1 * 32))[(size_t)node * 4 + p] = o;
    }
}

// ============ persistent MFMA MLP + residual + LayerNorm (sliced I/O) ============
__global__ void __launch_bounds__(512, 2) k_mlp(
        const ushort_t* __restrict__ z16,
        const ushort_t* __restrict__ h16i, ushort_t* __restrict__ h16o,
        const int layer,
        const ushort_t* __restrict__ W1t, const float* __restrict__ b1,
        const ushort_t* __restrict__ W2t, const float* __restrict__ b2,
        const float* __restrict__ lng, const float* __restrict__ lnb) {
    __shared__ ushort_t ts[32 * 256];        // 16 KB, XOR-swizzled (512 B rows)
    __shared__ float red[2][16][4][2];       // cross-wave LN partials
    const int t = threadIdx.x;
    const int lane = t & 63, w = t >> 6;     // 8 waves
    const int lr = lane & 15, lk = lane >> 4;
    const int rt_w = w & 1, ch = w >> 1;     // ch = col-slice (0..3)

    // ---- register-cache weight fragments (once per block) ----
    const ushort_t* W1p = W1t + (size_t)layer * 256 * 128;
    const ushort_t* W2p = W2t + (size_t)layer * 128 * 256;
    bf16x8 fa1[2][4];
    #pragma unroll
    for (int nt = 0; nt < 2; ++nt)
        #pragma unroll
        for (int kk = 0; kk < 4; ++kk)
            fa1[nt][kk] = *(const bf16x8*)(W1p + (size_t)((w * 2 + nt) * 16 + lr) * 128 + kk * 32 + lk * 8);
    bf16x8 fa2[2][8];
    #pragma unroll
    for (int nt = 0; nt < 2; ++nt)
        #pragma unroll
        for (int kk = 0; kk < 8; ++kk)
            fa2[nt][kk] = *(const bf16x8*)(W2p + (size_t)((ch * 2 + nt) * 16 + lr) * 256 + kk * 32 + lk * 8);

    // per-lane bias/LN params (fixed columns)
    float4 bb1[2], bb2[2], g4[2], be4[2];
    #pragma unroll
    for (int nt = 0; nt < 2; ++nt) {
        bb1[nt] = *(const float4*)&b1[layer * 256 + (w * 2 + nt) * 16 + lk * 4];
        const int c = (ch * 2 + nt) * 16 + lk * 4;
        bb2[nt] = *(const float4*)&b2[layer * 128 + c];
        g4[nt]  = *(const float4*)&lng[layer * 128 + c];
        be4[nt] = *(const float4*)&lnb[layer * 128 + c];
    }

    const int NT = (NN + 31) / 32;
    const int myrow = rt_w * 16 + lr;
    for (int tile = blockIdx.x; tile < NT; tile += gridDim.x) {
        const int row0 = tile * 32;
        const int node = row0 + myrow;

        // residual prefetch
        uint2 hres[2] = {{0u, 0u}, {0u, 0u}};
        if (node < NN) {
            #pragma unroll
            for (int nt = 0; nt < 2; ++nt)
                hres[nt] = *(const uint2*)&h16i[((size_t)ch * NN1 + node) * 32 + nt * 16 + lk * 4];
        }

        // ---- phase 1: C1^T = W1(A) x z(B); z slice = kk exactly ----
        f32x4 acc1[2][2];
        #pragma unroll
        for (int nt = 0; nt < 2; ++nt)
            #pragma unroll
            for (int rt = 0; rt < 2; ++rt) acc1[nt][rt] = (f32x4){0.f, 0.f, 0.f, 0.f};
        #pragma unroll
        for (int kk = 0; kk < 4; ++kk) {
            bf16x8 bv[2];
            #pragma unroll
            for (int rt = 0; rt < 2; ++rt) {
                const int zrow = row0 + rt * 16 + lr;
                bv[rt] = (zrow < NN)
                    ? *(const bf16x8*)(z16 + ((size_t)kk * NN1 + zrow) * 32 + lk * 8)
                    : (bf16x8){0, 0, 0, 0, 0, 0, 0, 0};
            }
            #pragma unroll
            for (int nt = 0; nt < 2; ++nt)
                #pragma unroll
                for (int rt = 0; rt < 2; ++rt)
                    acc1[nt][rt] = __builtin_amdgcn_mfma_f32_16x16x32_bf16(fa1[nt][kk], bv[rt], acc1[nt][rt], 0, 0, 0);
        }
        // bias + relu -> ts (lane holds 4 consecutive n-cols at one z-row)
        #pragma unroll
        for (int nt = 0; nt < 2; ++nt) {
            const int nc = (w * 2 + nt) * 16 + lk * 4;
            #pragma unroll
            for (int rt = 0; rt < 2; ++rt) {
                const int zrow = rt * 16 + lr;
                unsigned lo = pk2(fmaxf(acc1[nt][rt][0] + bb1[nt].x, 0.f),
                                  fmaxf(acc1[nt][rt][1] + bb1[nt].y, 0.f));
                unsigned hi = pk2(fmaxf(acc1[nt][rt][2] + bb1[nt].z, 0.f),
                                  fmaxf(acc1[nt][rt][3] + bb1[nt].w, 0.f));
                const int byte = (zrow * 512 + nc * 2) ^ ((zrow & 7) << 4);
                uint2 o; o.x = lo; o.y = hi;
                *(uint2*)((char*)ts + byte) = o;
            }
        }
        __syncthreads();

        // ---- phase 2: C2^T = W2(A) x t(B); rows rt_w*16.., cols ch*32.. ----
        f32x4 acc2[2];
        acc2[0] = (f32x4){0.f, 0.f, 0.f, 0.f};
        acc2[1] = (f32x4){0.f, 0.f, 0.f, 0.f};
        #pragma unroll
        for (int kk = 0; kk < 8; ++kk) {
            const int byte = (myrow * 512 + kk * 64 + lk * 16) ^ ((myrow & 7) << 4);
            const bf16x8 bv = *(const bf16x8*)((const char*)ts + byte);
            acc2[0] = __builtin_amdgcn_mfma_f32_16x16x32_bf16(fa2[0][kk], bv, acc2[0], 0, 0, 0);
            acc2[1] = __builtin_amdgcn_mfma_f32_16x16x32_bf16(fa2[1][kk], bv, acc2[1], 0, 0, 0);
        }

        // ---- bias + residual + LN partials (lane: 8 cols of row `myrow`) ----
        float vals[2][4];
        float s = 0.f, ss = 0.f;
        #pragma unroll
        for (int nt = 0; nt < 2; ++nt) {
            float v0 = acc2[nt][0] + bb2[nt].x + bflo(hres[nt].x);
            float v1 = acc2[nt][1] + bb2[nt].y + bfhi(hres[nt].x);
            float v2 = acc2[nt][2] + bb2[nt].z + bflo(hres[nt].y);
            float v3 = acc2[nt][3] + bb2[nt].w + bfhi(hres[nt].y);
            vals[nt][0] = v0; vals[nt][1] = v1; vals[nt][2] = v2; vals[nt][3] = v3;
            s += v0 + v1 + v2 + v3;
            ss += v0 * v0 + v1 * v1 + v2 * v2 + v3 * v3;
        }
        s  += __shfl_xor(s, 16);  s  += __shfl_xor(s, 32);
        ss += __shfl_xor(ss, 16); ss += __shfl_xor(ss, 32);
        if (lk == 0) {
            red[rt_w][lr][ch][0] = s;
            red[rt_w][lr][ch][1] = ss;
        }
        __syncthreads();

        // cross-wave combine (4 col-slices per row)
        float st = red[rt_w][lr][0][0] + red[rt_w][lr][1][0] + red[rt_w][lr][2][0] + red[rt_w][lr][3][0];
        float sst = red[rt_w][lr][0][1] + red[rt_w][lr][1][1] + red[rt_w][lr][2][1] + red[rt_w][lr][3][1];
        const float mu = st * (1.f / 128.f);
        const float rstd = rsqrtf(sst * (1.f / 128.f) - mu * mu + 1e-5f);
        if (node < NN) {
            #pragma unroll
            for (int nt = 0; nt < 2; ++nt) {
                float o0 = (vals[nt][0] - mu) * rstd * g4[nt].x + be4[nt].x;
                float o1 = (vals[nt][1] - mu) * rstd * g4[nt].y + be4[nt].y;
                float o2 = (vals[nt][2] - mu) * rstd * g4[nt].z + be4[nt].z;
                float o3 = (vals[nt][3] - mu) * rstd * g4[nt].w + be4[nt].w;
                uint2 pkd; pkd.x = pk2(o0, o1); pkd.y = pk2(o2, o3);
                *(uint2*)&h16o[((size_t)ch * NN1 + node) * 32 + nt * 16 + lk * 4] = pkd;
            }
        }
    }
}

// ---------------- readout: out = h[roots] @ W_out (sliced h) ----------------
__global__ void __launch_bounds__(256) k_out(const ushort_t* __restrict__ h,
                                             const int* __restrict__ roots,
                                             const float* __restrict__ Wo,
                                             float* __restrict__ out) {
    __shared__ float hs[16 * 128];
    int t = threadIdx.x;
    int r0 = blockIdx.x * 16;
    for (int i = t; i < 16 * 32; i += 256) {
        int row = i >> 5, u = i & 31;
        const int sl = u >> 3, off = (u & 7) * 4;
        uint2 v = *(const uint2*)&h[((size_t)sl * NN1 + roots[r0 + row]) * 32 + off];
        hs[row * 128 + u * 4 + 0] = bflo(v.x);
        hs[row * 128 + u * 4 + 1] = bfhi(v.x);
        hs[row * 128 + u * 4 + 2] = bflo(v.y);
        hs[row * 128 + u * 4 + 3] = bfhi(v.y);
    }
    __syncthreads();
    for (int o = t; o < 16 * NO; o += 256) {
        int j = o / NO, c = o % NO;
        float s = 0.f;
        for (int k = 0; k < 128; ++k) s += hs[j * 128 + k] * Wo[k * NO + c];
        out[(r0 + j) * NO + c] = s;
    }
}

extern "C" void kernel_launch(void* const* d_in, const int* in_sizes, int n_in,
                              void* d_out, int out_size, void* d_ws, size_t ws_size,
                              hipStream_t stream) {
    const int*   x    = (const int*)d_in[0];
    const int*   ei   = (const int*)d_in[1];
    const int*   roots= (const int*)d_in[2];
    const float* ke   = (const float*)d_in[3];
    const float* ve   = (const float*)d_in[4];
    const float* eps  = (const float*)d_in[5];
    const float* W1   = (const float*)d_in[6];
    const float* b1   = (const float*)d_in[7];
    const float* W2   = (const float*)d_in[8];
    const float* b2   = (const float*)d_in[9];
    const float* g    = (const float*)d_in[10];
    const float* bt   = (const float*)d_in[11];
    const float* Wo   = (const float*)d_in[12];
    float* out = (float*)d_out;

    char* ws = (char*)d_ws;
    size_t off = 0;
    auto alloc = [&](size_t bytes) {
        void* p = ws + off;
        off += (bytes + 255) & ~(size_t)255;
        return p;
    };
    ushort_t* h16A = (ushort_t*)alloc((size_t)4 * NN1 * 32 * 2);
    ushort_t* h16B = (ushort_t*)alloc((size_t)4 * NN1 * 32 * 2);
    ushort_t* z16  = (ushort_t*)alloc((size_t)4 * NN1 * 32 * 2);
    ushort_t* W1tb = (ushort_t*)alloc((size_t)NL * 256 * 128 * 2);
    ushort_t* W2tb = (ushort_t*)alloc((size_t)NL * 128 * 256 * 2);
    int* deg  = (int*)alloc((size_t)NN * 4);
    int* incl = (int*)alloc((size_t)NN * 4);
    int* bsum = (int*)alloc(256 * 4);
    int* rs   = (int*)alloc((size_t)(NN + 1) * 4);
    int* cur  = (int*)alloc((size_t)NN * 4);
    ushort_t* csrc = (ushort_t*)alloc((size_t)1600000 * 2);   // padded CSR

    hipMemsetAsync(deg, 0, (size_t)NN * 4, stream);

    const int initTot = NN * 32 + 2 * NL * 32768 + 64;
    k_initw<<<(initTot + 255) / 256, 256, 0, stream>>>(x, ke, ve, h16A, h16B, W1, W1tb, W2, W2tb);
    k_hist<<<FILL_NB, 256, 0, stream>>>(ei, deg);
    int nb = (NN + 255) / 256;
    k_scan1<<<nb, 256, 0, stream>>>(deg, incl, bsum);
    k_scan2<<<1, 256, 0, stream>>>(bsum, nb);
    k_scan3<<<nb, 256, 0, stream>>>(deg, incl, bsum, rs, cur, csrc);
    k_fill<<<FILL_NB, 256, 0, stream>>>(ei, cur, csrc);

    const int aggBlocks = (NN / 16) * 4;   // 3125 node-blocks x 4 slices
    for (int l = 0; l < NL; ++l) {
        const ushort_t* hi = (l & 1) ? h16B : h16A;
        ushort_t*       ho = (l & 1) ? h16A : h16B;
        k_agg<<<aggBlocks, 256, 0, stream>>>(hi, rs, csrc, eps, l, z16);
        k_mlp<<<256, 512, 0, stream>>>(z16, hi, ho, l, W1tb, b1, W2tb, b2, g, bt);
    }
    k_out<<<NR / 16, 256, 0, stream>>>(h16B, roots, Wo, out);
}

// Round 19
// 380.816 us; speedup vs baseline: 1.5410x; 1.0118x over previous
//
#include <hip/hip_runtime.h>
#include <hip/hip_bf16.h>

#define NN 50000
#define NN1 50001                 // +1 zero-node row (gather padding target)
#define NE 800000
#define D 128
#define NL 5
#define NR 2048
#define NO 65
#define FILL_NB 1024
#define INIT_NB 7531              // ceil((NN*32 + 2*NL*32768 + 64)/256)

typedef unsigned short ushort_t;
typedef __attribute__((ext_vector_type(8))) short bf16x8;
typedef __attribute__((ext_vector_type(4))) float f32x4;

// h16/z16 stored SLICE-MAJOR: [4][NN1][32] bf16 — dim d of node n lives at
// ((d>>5)*NN1 + n)*32 + (d&31). Row NN is all-zero (padding target).

__device__ inline float bflo(unsigned u) {
    return __builtin_bit_cast(float, u << 16);
}
__device__ inline float bfhi(unsigned u) {
    return __builtin_bit_cast(float, u & 0xFFFF0000u);
}
__device__ inline ushort_t f2bf(float f) {
    unsigned u = __builtin_bit_cast(unsigned, f);
    u = (u + 0x7FFF + ((u >> 16) & 1)) >> 16;   // RNE
    return (ushort_t)u;
}
__device__ inline unsigned pk2(float a, float b) {
    return (unsigned)f2bf(a) | ((unsigned)f2bf(b) << 16);
}
__device__ inline void acc8(float* a, uint4 v) {
    a[0] += bflo(v.x); a[1] += bfhi(v.x);
    a[2] += bflo(v.y); a[3] += bfhi(v.y);
    a[4] += bflo(v.z); a[5] += bfhi(v.z);
    a[6] += bflo(v.w); a[7] += bfhi(v.w);
}

// ---- combined init: h0 (sliced bf16) + W1t/W2t transpose + zero rows +
// ---- XCD-partitioned degree histogram (blocks >= INIT_NB) ----
__global__ void k_initw(const int* __restrict__ x, const float* __restrict__ ke,
                        const float* __restrict__ ve, ushort_t* __restrict__ h16A,
                        ushort_t* __restrict__ h16B,
                        const float* __restrict__ W1, ushort_t* __restrict__ W1t,
                        const float* __restrict__ W2, ushort_t* __restrict__ W2t,
                        const int* __restrict__ ei, int* __restrict__ deg) {
    if (blockIdx.x >= INIT_NB) {
        // histogram portion: partition = blockIdx&7 (XCD-pinned), j = local idx
        const int part = blockIdx.x & 7;
        const int j = (blockIdx.x - INIT_NB) >> 3;
        const int lo = part * (NN / 8), hi = lo + (NN / 8);
        for (int e = j * 256 + threadIdx.x; e < NE; e += (FILL_NB / 8) * 256) {
            const int d = ei[NE + e];
            if (d >= lo && d < hi) atomicAdd(&deg[d], 1);
        }
        return;
    }
    int i = blockIdx.x * blockDim.x + threadIdx.x;
    if (i < NN * 32) {
        int node = i >> 5, f4 = (i & 31) * 4;
        float4 a = *(const float4*)&ke[(size_t)x[node * 2 + 0] * D + f4];
        float4 b = *(const float4*)&ve[(size_t)x[node * 2 + 1] * D + f4];
        uint2 o;
        o.x = pk2(a.x + b.x, a.y + b.y);
        o.y = pk2(a.z + b.z, a.w + b.w);
        const int s = f4 >> 5, off = f4 & 31;
        *(uint2*)&h16A[((size_t)s * NN1 + node) * 32 + off] = o;
        return;
    }
    int j = i - NN * 32;
    if (j < NL * 32768) {               // W1t[l][n(256)][k(128)]
        int l = j / 32768, r = j % 32768;
        int n = r >> 7, k = r & 127;
        W1t[j] = f2bf(W1[l * 32768 + k * 256 + n]);
        return;
    }
    j -= NL * 32768;
    if (j < NL * 32768) {               // W2t[l][n(128)][k(256)]
        int l = j / 32768, r = j % 32768;
        int n = r >> 8, k = r & 255;
        W2t[j] = f2bf(W2[l * 32768 + k * 128 + n]);
        return;
    }
    j -= NL * 32768;
    if (j < 64) {                       // zero rows (node NN) for both buffers
        ushort_t* buf = (j >> 5) ? h16B : h16A;
        const int r = j & 31;
        const int s = r >> 3, off = (r & 7) * 4;
        uint2 z = {0u, 0u};
        *(uint2*)&buf[((size_t)s * NN1 + NN) * 32 + off] = z;
    }
}

// scan1 on PADDED degrees: bsums[b] = inclusive total of block b
__global__ void k_scan1(const int* __restrict__ deg, int* __restrict__ incl,
                        int* __restrict__ bsums) {
    __shared__ int s[256];
    int t = threadIdx.x, i = blockIdx.x * 256 + t;
    int v = (i < NN) ? ((deg[i] + 15) & ~15) : 0;
    s[t] = v; __syncthreads();
    for (int off = 1; off < 256; off <<= 1) {
        int u = (t >= off) ? s[t - off] : 0;
        __syncthreads();
        s[t] += u; __syncthreads();
    }
    if (i < NN) incl[i] = s[t];
    if (t == 255) bsums[blockIdx.x] = s[255];
}

// scan3 (+inlined scan2): each block locally sums bsums[0..blockIdx) for its
// prefix, writes padded starts + zero-node fillers into the pad region.
__global__ void k_scan3(const int* __restrict__ deg, const int* __restrict__ incl,
                        const int* __restrict__ bsums, int* __restrict__ rs,
                        int* __restrict__ cur, ushort_t* __restrict__ csrc) {
    __shared__ int s[256];
    const int t = threadIdx.x;
    int v = (t < (int)blockIdx.x) ? bsums[t] : 0;   // nb = 196 <= 256
    s[t] = v; __syncthreads();
    for (int off = 1; off < 256; off <<= 1) {
        int u = (t >= off) ? s[t - off] : 0;
        __syncthreads();
        s[t] += u; __syncthreads();
    }
    const int prefix = s[255];
    const int i = blockIdx.x * 256 + t;
    if (i >= NN) return;
    const int d = deg[i];
    const int pd = (d + 15) & ~15;
    int ex = incl[i] - pd + prefix;
    rs[i] = ex; cur[i] = ex;
    for (int j = ex + d; j < ex + pd; ++j) csrc[j] = (ushort_t)NN;
    if (i == NN - 1) rs[NN] = ex + pd;
}

// XCD-partitioned fill (writes real edges; pad slots pre-filled by k_scan3).
__global__ void k_fill(const int* __restrict__ ei, int* __restrict__ cur,
                       ushort_t* __restrict__ csrc) {
    const int part = blockIdx.x & 7;
    const int j = blockIdx.x >> 3;
    const int lo = part * (NN / 8), hi = lo + (NN / 8);
    for (int e = j * 256 + threadIdx.x; e < NE; e += (FILL_NB / 8) * 256) {
        const int d = ei[NE + e];
        if (d >= lo && d < hi) {
            const int pos = atomicAdd(&cur[d], 1);
            csrc[pos] = (ushort_t)ei[e];    // src < 50000 < 65536
        }
    }
}

// ------- aggregate (sliced): z16[s] = bf16((1+eps)*h[s] + sum_in h[s][src]) -----
// block = 256 thr = 4 waves, 16 nodes x ONE 32-dim slice (blockIdx&3; XCD-pinned).
// wave: 4 nodes (grp), 4 edge-phases (q) x batch-4; padded CSR -> NO bounds checks.
__global__ void __launch_bounds__(256) k_agg(const ushort_t* __restrict__ h16,
                                             const int* __restrict__ rs,
                                             const ushort_t* __restrict__ csrc,
                                             const float* __restrict__ epsArr, int layer,
                                             ushort_t* __restrict__ z16) {
    const int s = blockIdx.x & 3;
    const int nb = blockIdx.x >> 2;
    const int wv = threadIdx.x >> 6;
    const int lane = threadIdx.x & 63;
    const int grp = lane >> 4;            // which of the wave's 4 nodes
    const int q = (lane >> 2) & 3;        // edge phase (4)
    const int p = lane & 3;               // which uint4 of the 64B slice row
    const int node = nb * 16 + wv * 4 + grp;    // 3125*16 == NN exactly
    const uint4* H4 = (const uint4*)(h16 + (size_t)s * NN1 * 32);
    const int myE0 = rs[node], myE1 = rs[node + 1];   // padded: multiple of 16
    const uint4 own = H4[(size_t)node * 4 + p];
    float acc[8] = {0.f, 0.f, 0.f, 0.f, 0.f, 0.f, 0.f, 0.f};
    for (int e = myE0 + q; e < myE1; e += 16) {
        const int ia = csrc[e];
        const int ib = csrc[e + 4];
        const int ic = csrc[e + 8];
        const int id = csrc[e + 12];
        acc8(acc, H4[(size_t)ia * 4 + p]);
        acc8(acc, H4[(size_t)ib * 4 + p]);
        acc8(acc, H4[(size_t)ic * 4 + p]);
        acc8(acc, H4[(size_t)id * 4 + p]);
    }
    #pragma unroll
    for (int k = 0; k < 8; ++k) {         // reduce over q bits (4,8); grp,p kept
        acc[k] += __shfl_xor(acc[k], 4);
        acc[k] += __shfl_xor(acc[k], 8);
    }
    if (q == 0) {
        const float epsl = 1.f + epsArr[layer];
        float r0 = acc[0] + epsl * bflo(own.x), r1 = acc[1] + epsl * bfhi(own.x);
        float r2 = acc[2] + epsl * bflo(own.y), r3 = acc[3] + epsl * bfhi(own.y);
        float r4 = acc[4] + epsl * bflo(own.z), r5 = acc[5] + epsl * bfhi(own.z);
        float r6 = acc[6] + epsl * bflo(own.w), r7 = acc[7] + epsl * bfhi(own.w);
        uint4 o;
        o.x = pk2(r0, r1); o.y = pk2(r2, r3);
        o.z = pk2(r4, r5); o.w = pk2(r6, r7);
        ((uint4*)(z16 + (size_t)s * NN1 * 32))[(size_t)node * 4 + p] = o;
    }
}

// ============ persistent MFMA MLP + residual + LayerNorm (sliced I/O) ============
__global__ void __launch_bounds__(512, 2) k_mlp(
        const ushort_t* __restrict__ z16,
        const ushort_t* __restrict__ h16i, ushort_t* __restrict__ h16o,
        const int layer,
        const ushort_t* __restrict__ W1t, const float* __restrict__ b1,
        const ushort_t* __restrict__ W2t, const float* __restrict__ b2,
        const float* __restrict__ lng, const float* __restrict__ lnb) {
    __shared__ ushort_t ts[32 * 256];        // 16 KB, XOR-swizzled (512 B rows)
    __shared__ float red[2][16][4][2];       // cross-wave LN partials
    const int t = threadIdx.x;
    const int lane = t & 63, w = t >> 6;     // 8 waves
    const int lr = lane & 15, lk = lane >> 4;
    const int rt_w = w & 1, ch = w >> 1;     // ch = col-slice (0..3)

    // ---- register-cache weight fragments (once per block) ----
    const ushort_t* W1p = W1t + (size_t)layer * 256 * 128;
    const ushort_t* W2p = W2t + (size_t)layer * 128 * 256;
    bf16x8 fa1[2][4];
    #pragma unroll
    for (int nt = 0; nt < 2; ++nt)
        #pragma unroll
        for (int kk = 0; kk < 4; ++kk)
            fa1[nt][kk] = *(const bf16x8*)(W1p + (size_t)((w * 2 + nt) * 16 + lr) * 128 + kk * 32 + lk * 8);
    bf16x8 fa2[2][8];
    #pragma unroll
    for (int nt = 0; nt < 2; ++nt)
        #pragma unroll
        for (int kk = 0; kk < 8; ++kk)
            fa2[nt][kk] = *(const bf16x8*)(W2p + (size_t)((ch * 2 + nt) * 16 + lr) * 256 + kk * 32 + lk * 8);

    // per-lane bias/LN params (fixed columns)
    float4 bb1[2], bb2[2], g4[2], be4[2];
    #pragma unroll
    for (int nt = 0; nt < 2; ++nt) {
        bb1[nt] = *(const float4*)&b1[layer * 256 + (w * 2 + nt) * 16 + lk * 4];
        const int c = (ch * 2 + nt) * 16 + lk * 4;
        bb2[nt] = *(const float4*)&b2[layer * 128 + c];
        g4[nt]  = *(const float4*)&lng[layer * 128 + c];
        be4[nt] = *(const float4*)&lnb[layer * 128 + c];
    }

    const int NT = (NN + 31) / 32;
    const int myrow = rt_w * 16 + lr;
    for (int tile = blockIdx.x; tile < NT; tile += gridDim.x) {
        const int row0 = tile * 32;
        const int node = row0 + myrow;

        // residual prefetch
        uint2 hres[2] = {{0u, 0u}, {0u, 0u}};
        if (node < NN) {
            #pragma unroll
            for (int nt = 0; nt < 2; ++nt)
                hres[nt] = *(const uint2*)&h16i[((size_t)ch * NN1 + node) * 32 + nt * 16 + lk * 4];
        }

        // ---- phase 1: C1^T = W1(A) x z(B); z slice = kk exactly ----
        f32x4 acc1[2][2];
        #pragma unroll
        for (int nt = 0; nt < 2; ++nt)
            #pragma unroll
            for (int rt = 0; rt < 2; ++rt) acc1[nt][rt] = (f32x4){0.f, 0.f, 0.f, 0.f};
        #pragma unroll
        for (int kk = 0; kk < 4; ++kk) {
            bf16x8 bv[2];
            #pragma unroll
            for (int rt = 0; rt < 2; ++rt) {
                const int zrow = row0 + rt * 16 + lr;
                bv[rt] = (zrow < NN)
                    ? *(const bf16x8*)(z16 + ((size_t)kk * NN1 + zrow) * 32 + lk * 8)
                    : (bf16x8){0, 0, 0, 0, 0, 0, 0, 0};
            }
            #pragma unroll
            for (int nt = 0; nt < 2; ++nt)
                #pragma unroll
                for (int rt = 0; rt < 2; ++rt)
                    acc1[nt][rt] = __builtin_amdgcn_mfma_f32_16x16x32_bf16(fa1[nt][kk], bv[rt], acc1[nt][rt], 0, 0, 0);
        }
        // bias + relu -> ts (lane holds 4 consecutive n-cols at one z-row)
        #pragma unroll
        for (int nt = 0; nt < 2; ++nt) {
            const int nc = (w * 2 + nt) * 16 + lk * 4;
            #pragma unroll
            for (int rt = 0; rt < 2; ++rt) {
                const int zrow = rt * 16 + lr;
                unsigned lo = pk2(fmaxf(acc1[nt][rt][0] + bb1[nt].x, 0.f),
                                  fmaxf(acc1[nt][rt][1] + bb1[nt].y, 0.f));
                unsigned hi = pk2(fmaxf(acc1[nt][rt][2] + bb1[nt].z, 0.f),
                                  fmaxf(acc1[nt][rt][3] + bb1[nt].w, 0.f));
                const int byte = (zrow * 512 + nc * 2) ^ ((zrow & 7) << 4);
                uint2 o; o.x = lo; o.y = hi;
                *(uint2*)((char*)ts + byte) = o;
            }
        }
        __syncthreads();

        // ---- phase 2: C2^T = W2(A) x t(B); rows rt_w*16.., cols ch*32.. ----
        f32x4 acc2[2];
        acc2[0] = (f32x4){0.f, 0.f, 0.f, 0.f};
        acc2[1] = (f32x4){0.f, 0.f, 0.f, 0.f};
        #pragma unroll
        for (int kk = 0; kk < 8; ++kk) {
            const int byte = (myrow * 512 + kk * 64 + lk * 16) ^ ((myrow & 7) << 4);
            const bf16x8 bv = *(const bf16x8*)((const char*)ts + byte);
            acc2[0] = __builtin_amdgcn_mfma_f32_16x16x32_bf16(fa2[0][kk], bv, acc2[0], 0, 0, 0);
            acc2[1] = __builtin_amdgcn_mfma_f32_16x16x32_bf16(fa2[1][kk], bv, acc2[1], 0, 0, 0);
        }

        // ---- bias + residual + LN partials (lane: 8 cols of row `myrow`) ----
        float vals[2][4];
        float s = 0.f, ss = 0.f;
        #pragma unroll
        for (int nt = 0; nt < 2; ++nt) {
            float v0 = acc2[nt][0] + bb2[nt].x + bflo(hres[nt].x);
            float v1 = acc2[nt][1] + bb2[nt].y + bfhi(hres[nt].x);
            float v2 = acc2[nt][2] + bb2[nt].z + bflo(hres[nt].y);
            float v3 = acc2[nt][3] + bb2[nt].w + bfhi(hres[nt].y);
            vals[nt][0] = v0; vals[nt][1] = v1; vals[nt][2] = v2; vals[nt][3] = v3;
            s += v0 + v1 + v2 + v3;
            ss += v0 * v0 + v1 * v1 + v2 * v2 + v3 * v3;
        }
        s  += __shfl_xor(s, 16);  s  += __shfl_xor(s, 32);
        ss += __shfl_xor(ss, 16); ss += __shfl_xor(ss, 32);
        if (lk == 0) {
            red[rt_w][lr][ch][0] = s;
            red[rt_w][lr][ch][1] = ss;
        }
        __syncthreads();

        // cross-wave combine (4 col-slices per row)
        float st = red[rt_w][lr][0][0] + red[rt_w][lr][1][0] + red[rt_w][lr][2][0] + red[rt_w][lr][3][0];
        float sst = red[rt_w][lr][0][1] + red[rt_w][lr][1][1] + red[rt_w][lr][2][1] + red[rt_w][lr][3][1];
        const float mu = st * (1.f / 128.f);
        const float rstd = rsqrtf(sst * (1.f / 128.f) - mu * mu + 1e-5f);
        if (node < NN) {
            #pragma unroll
            for (int nt = 0; nt < 2; ++nt) {
                float o0 = (vals[nt][0] - mu) * rstd * g4[nt].x + be4[nt].x;
                float o1 = (vals[nt][1] - mu) * rstd * g4[nt].y + be4[nt].y;
                float o2 = (vals[nt][2] - mu) * rstd * g4[nt].z + be4[nt].z;
                float o3 = (vals[nt][3] - mu) * rstd * g4[nt].w + be4[nt].w;
                uint2 pkd; pkd.x = pk2(o0, o1); pkd.y = pk2(o2, o3);
                *(uint2*)&h16o[((size_t)ch * NN1 + node) * 32 + nt * 16 + lk * 4] = pkd;
            }
        }
    }
}

// ---------------- readout: out = h[roots] @ W_out (sliced h) ----------------
__global__ void __launch_bounds__(256) k_out(const ushort_t* __restrict__ h,
                                             const int* __restrict__ roots,
                                             const float* __restrict__ Wo,
                                             float* __restrict__ out) {
    __shared__ float hs[16 * 128];
    int t = threadIdx.x;
    int r0 = blockIdx.x * 16;
    for (int i = t; i < 16 * 32; i += 256) {
        int row = i >> 5, u = i & 31;
        const int sl = u >> 3, off = (u & 7) * 4;
        uint2 v = *(const uint2*)&h[((size_t)sl * NN1 + roots[r0 + row]) * 32 + off];
        hs[row * 128 + u * 4 + 0] = bflo(v.x);
        hs[row * 128 + u * 4 + 1] = bfhi(v.x);
        hs[row * 128 + u * 4 + 2] = bflo(v.y);
        hs[row * 128 + u * 4 + 3] = bfhi(v.y);
    }
    __syncthreads();
    for (int o = t; o < 16 * NO; o += 256) {
        int j = o / NO, c = o % NO;
        float s = 0.f;
        for (int k = 0; k < 128; ++k) s += hs[j * 128 + k] * Wo[k * NO + c];
        out[(r0 + j) * NO + c] = s;
    }
}

extern "C" void kernel_launch(void* const* d_in, const int* in_sizes, int n_in,
                              void* d_out, int out_size, void* d_ws, size_t ws_size,
                              hipStream_t stream) {
    const int*   x    = (const int*)d_in[0];
    const int*   ei   = (const int*)d_in[1];
    const int*   roots= (const int*)d_in[2];
    const float* ke   = (const float*)d_in[3];
    const float* ve   = (const float*)d_in[4];
    const float* eps  = (const float*)d_in[5];
    const float* W1   = (const float*)d_in[6];
    const float* b1   = (const float*)d_in[7];
    const float* W2   = (const float*)d_in[8];
    const float* b2   = (const float*)d_in[9];
    const float* g    = (const float*)d_in[10];
    const float* bt   = (const float*)d_in[11];
    const float* Wo   = (const float*)d_in[12];
    float* out = (float*)d_out;

    char* ws = (char*)d_ws;
    size_t off = 0;
    auto alloc = [&](size_t bytes) {
        void* p = ws + off;
        off += (bytes + 255) & ~(size_t)255;
        return p;
    };
    ushort_t* h16A = (ushort_t*)alloc((size_t)4 * NN1 * 32 * 2);
    ushort_t* h16B = (ushort_t*)alloc((size_t)4 * NN1 * 32 * 2);
    ushort_t* z16  = (ushort_t*)alloc((size_t)4 * NN1 * 32 * 2);
    ushort_t* W1tb = (ushort_t*)alloc((size_t)NL * 256 * 128 * 2);
    ushort_t* W2tb = (ushort_t*)alloc((size_t)NL * 128 * 256 * 2);
    int* deg  = (int*)alloc((size_t)NN * 4);
    int* incl = (int*)alloc((size_t)NN * 4);
    int* bsum = (int*)alloc(256 * 4);
    int* rs   = (int*)alloc((size_t)(NN + 1) * 4);
    int* cur  = (int*)alloc((size_t)NN * 4);
    ushort_t* csrc = (ushort_t*)alloc((size_t)1600000 * 2);   // padded CSR

    hipMemsetAsync(deg, 0, (size_t)NN * 4, stream);

    k_initw<<<INIT_NB + FILL_NB, 256, 0, stream>>>(x, ke, ve, h16A, h16B, W1, W1tb, W2, W2tb, ei, deg);
    int nb = (NN + 255) / 256;
    k_scan1<<<nb, 256, 0, stream>>>(deg, incl, bsum);
    k_scan3<<<nb, 256, 0, stream>>>(deg, incl, bsum, rs, cur, csrc);
    k_fill<<<FILL_NB, 256, 0, stream>>>(ei, cur, csrc);

    const int aggBlocks = (NN / 16) * 4;   // 3125 node-blocks x 4 slices
    for (int l = 0; l < NL; ++l) {
        const ushort_t* hi = (l & 1) ? h16B : h16A;
        ushort_t*       ho = (l & 1) ? h16A : h16B;
        k_agg<<<aggBlocks, 256, 0, stream>>>(hi, rs, csrc, eps, l, z16);
        k_mlp<<<256, 512, 0, stream>>>(z16, hi, ho, l, W1tb, b1, W2tb, b2, g, bt);
    }
    k_out<<<NR / 16, 256, 0, stream>>>(h16B, roots, Wo, out);
}